// Round 3
// baseline (350.373 us; speedup 1.0000x reference)
//
#include <hip/hip_runtime.h>

typedef _Float16 half8 __attribute__((ext_vector_type(8)));
typedef _Float16 half4 __attribute__((ext_vector_type(4)));
typedef float floatx4 __attribute__((ext_vector_type(4)));

// ---------------- GEMM1: qkv = x @ w_qkv^T, split epilogue to head-major q/k/vt --
// M=4096, N=3072, K=1024. 128x128 tile, BK=32, 256 threads. Inputs fp32, out fp16.
__global__ __launch_bounds__(256) void gemm_qkv(const float* __restrict__ X,
                                                const float* __restrict__ W,
                                                _Float16* __restrict__ qh,
                                                _Float16* __restrict__ kh,
                                                _Float16* __restrict__ vth) {
    const int K = 1024;
    __shared__ _Float16 As[128 * 32];
    __shared__ _Float16 Bs[128 * 32];
    const int t = threadIdx.x;
    const int lane = t & 63, w = t >> 6;
    const int l15 = lane & 15, quad = lane >> 4;
    const int wm = w >> 1, wn = w & 1;
    const int m0 = blockIdx.y * 128, n0 = blockIdx.x * 128;

    floatx4 acc[4][4];
    const floatx4 zf = {0.f, 0.f, 0.f, 0.f};
#pragma unroll
    for (int i = 0; i < 4; ++i)
#pragma unroll
        for (int j = 0; j < 4; ++j) acc[i][j] = zf;

    for (int kt = 0; kt < K; kt += 32) {
        __syncthreads();
#pragma unroll
        for (int it = 0; it < 4; ++it) {
            int cc = it * 256 + t;          // 1024 chunks of 4 floats
            int row = cc >> 3, c4 = cc & 7;
            floatx4 xv = *(const floatx4*)&X[(size_t)(m0 + row) * K + kt + c4 * 4];
            floatx4 wv = *(const floatx4*)&W[(size_t)(n0 + row) * K + kt + c4 * 4];
            half4 xh, wh;
#pragma unroll
            for (int j = 0; j < 4; ++j) { xh[j] = (_Float16)xv[j]; wh[j] = (_Float16)wv[j]; }
            *(half4*)&As[row * 32 + c4 * 4] = xh;
            *(half4*)&Bs[row * 32 + c4 * 4] = wh;
        }
        __syncthreads();
        half8 af[4], bfr[4];
#pragma unroll
        for (int i = 0; i < 4; ++i)
            af[i] = *(const half8*)&As[(wm * 64 + i * 16 + l15) * 32 + quad * 8];
#pragma unroll
        for (int i = 0; i < 4; ++i)
            bfr[i] = *(const half8*)&Bs[(wn * 64 + i * 16 + l15) * 32 + quad * 8];
#pragma unroll
        for (int mi = 0; mi < 4; ++mi)
#pragma unroll
            for (int ni = 0; ni < 4; ++ni)
                acc[mi][ni] = __builtin_amdgcn_mfma_f32_16x16x32_f16(af[mi], bfr[ni],
                                                                     acc[mi][ni], 0, 0, 0);
    }

#pragma unroll
    for (int mi = 0; mi < 4; ++mi) {
#pragma unroll
        for (int ni = 0; ni < 4; ++ni) {
            int col = n0 + wn * 64 + ni * 16 + l15;
#pragma unroll
            for (int r = 0; r < 4; ++r) {
                int row = m0 + wm * 64 + mi * 16 + quad * 4 + r;
                int b = row >> 11, s = row & 2047;
                _Float16 hv = (_Float16)acc[mi][ni][r];
                if (col < 1024) {
                    qh[(size_t)((b << 4) | (col >> 6)) * 131072 + s * 64 + (col & 63)] = hv;
                } else if (col < 2048) {
                    int c = col - 1024;
                    kh[(size_t)((b << 4) | (c >> 6)) * 131072 + s * 64 + (c & 63)] = hv;
                } else {
                    int c = col - 2048;
                    vth[(size_t)((b << 4) | (c >> 6)) * 131072 + (c & 63) * 2048 + s] = hv;
                }
            }
        }
    }
}

// ---------------- GEMM2: out = aoh @ w_out^T + b_out -> fp32 ---------------------
// M=4096, N=1024, K=1024. A fp16, W fp32, C fp32.
__global__ __launch_bounds__(256) void gemm_out(const _Float16* __restrict__ A,
                                                const float* __restrict__ W,
                                                float* __restrict__ C,
                                                const float* __restrict__ bias) {
    const int K = 1024, N = 1024;
    __shared__ _Float16 As[128 * 32];
    __shared__ _Float16 Bs[128 * 32];
    const int t = threadIdx.x;
    const int lane = t & 63, w = t >> 6;
    const int l15 = lane & 15, quad = lane >> 4;
    const int wm = w >> 1, wn = w & 1;
    const int m0 = blockIdx.y * 128, n0 = blockIdx.x * 128;

    floatx4 acc[4][4];
    const floatx4 zf = {0.f, 0.f, 0.f, 0.f};
#pragma unroll
    for (int i = 0; i < 4; ++i)
#pragma unroll
        for (int j = 0; j < 4; ++j) acc[i][j] = zf;

    for (int kt = 0; kt < K; kt += 32) {
        __syncthreads();
#pragma unroll
        for (int it = 0; it < 2; ++it) {        // A: fp16 source, 512 chunks of 8
            int cc = it * 256 + t;
            int row = cc >> 2, kc = cc & 3;
            *(half8*)&As[row * 32 + kc * 8] =
                *(const half8*)&A[(size_t)(m0 + row) * K + kt + kc * 8];
        }
#pragma unroll
        for (int it = 0; it < 4; ++it) {        // B: fp32 source, 1024 chunks of 4
            int cc = it * 256 + t;
            int row = cc >> 3, c4 = cc & 7;
            floatx4 wv = *(const floatx4*)&W[(size_t)(n0 + row) * K + kt + c4 * 4];
            half4 wh;
#pragma unroll
            for (int j = 0; j < 4; ++j) wh[j] = (_Float16)wv[j];
            *(half4*)&Bs[row * 32 + c4 * 4] = wh;
        }
        __syncthreads();
        half8 af[4], bfr[4];
#pragma unroll
        for (int i = 0; i < 4; ++i)
            af[i] = *(const half8*)&As[(wm * 64 + i * 16 + l15) * 32 + quad * 8];
#pragma unroll
        for (int i = 0; i < 4; ++i)
            bfr[i] = *(const half8*)&Bs[(wn * 64 + i * 16 + l15) * 32 + quad * 8];
#pragma unroll
        for (int mi = 0; mi < 4; ++mi)
#pragma unroll
            for (int ni = 0; ni < 4; ++ni)
                acc[mi][ni] = __builtin_amdgcn_mfma_f32_16x16x32_f16(af[mi], bfr[ni],
                                                                     acc[mi][ni], 0, 0, 0);
    }

#pragma unroll
    for (int mi = 0; mi < 4; ++mi) {
#pragma unroll
        for (int ni = 0; ni < 4; ++ni) {
            int col = n0 + wn * 64 + ni * 16 + l15;
            float bv = bias[col];
#pragma unroll
            for (int r = 0; r < 4; ++r) {
                int row = m0 + wm * 64 + mi * 16 + quad * 4 + r;
                C[(size_t)row * N + col] = acc[mi][ni][r] + bv;
            }
        }
    }
}

// ---------------- stablemax3 s(x), fp32 -----------------------------------------
__device__ inline float s3fn(float x) {
    float tp = 1.f + x * (1.f / 3.f);
    float pos = 1.f + x * (1.f + 0.5f * x * tp);
    float tn = 1.f - x * (1.f / 3.f);
    float den = 1.f - x * (1.f - 0.5f * x * tn);
    return x >= 0.f ? pos : 1.f / den;
}

// ---------------- fused two-pass stablemax attention ----------------------------
// grid (S/128, B*H), 256 threads. QT=128, KT=64, hd=64. head-major fp16 inputs.
__global__ __launch_bounds__(256) void attn_kernel(const _Float16* __restrict__ qh,
                                                   const _Float16* __restrict__ kh,
                                                   const _Float16* __restrict__ vth,
                                                   _Float16* __restrict__ out) {
    __shared__ _Float16 Qs[128 * 64];   // 16 KB
    __shared__ _Float16 Ks[64 * 64];    // 8 KB
    __shared__ _Float16 VTs[64 * 64];   // 8 KB   VT[d][key]
    __shared__ _Float16 Ps[128 * 64];   // 16 KB  P[q][key]
    __shared__ float red[2][128];
    __shared__ float mrow[128];
    __shared__ float srow[128];

    const int t = threadIdx.x;
    const int lane = t & 63, w = t >> 6;
    const int l15 = lane & 15, quad = lane >> 4;
    const int wm = w >> 1, wn = w & 1;
    const int q0 = blockIdx.x * 128;
    const int bh = blockIdx.y;
    const int b = bh >> 4, h = bh & 15;

    const _Float16* Qp = qh + (size_t)bh * 131072 + q0 * 64;
    const _Float16* Kp = kh + (size_t)bh * 131072;
    const _Float16* VTp = vth + (size_t)bh * 131072;

    const floatx4 zf = {0.f, 0.f, 0.f, 0.f};

    // load Q tile: 128 rows x 64 cols, fully contiguous in head-major layout
#pragma unroll
    for (int it = 0; it < 4; ++it) {
        int cc = it * 256 + t;
        *(half8*)&Qs[cc * 8] = *(const half8*)&Qp[cc * 8];
    }

    // ---------------- pass 1: row max of raw dot (scale folded out; scale>0) ----
    float rmax[16];
#pragma unroll
    for (int i = 0; i < 16; ++i) rmax[i] = -3.0e38f;

    for (int kt = 0; kt < 2048; kt += 64) {
        __syncthreads();
#pragma unroll
        for (int it = 0; it < 2; ++it) {
            int cc = it * 256 + t;
            *(half8*)&Ks[cc * 8] = *(const half8*)&Kp[kt * 64 + cc * 8];
        }
        __syncthreads();
        floatx4 sa[4][2];
#pragma unroll
        for (int mi = 0; mi < 4; ++mi) { sa[mi][0] = zf; sa[mi][1] = zf; }
#pragma unroll
        for (int kk = 0; kk < 2; ++kk) {
            half8 af[4], bfr[2];
#pragma unroll
            for (int mi = 0; mi < 4; ++mi)
                af[mi] = *(const half8*)&Qs[(wm * 64 + mi * 16 + l15) * 64 + kk * 32 + quad * 8];
#pragma unroll
            for (int ni = 0; ni < 2; ++ni)
                bfr[ni] = *(const half8*)&Ks[(wn * 32 + ni * 16 + l15) * 64 + kk * 32 + quad * 8];
#pragma unroll
            for (int mi = 0; mi < 4; ++mi)
#pragma unroll
                for (int ni = 0; ni < 2; ++ni)
                    sa[mi][ni] = __builtin_amdgcn_mfma_f32_16x16x32_f16(af[mi], bfr[ni],
                                                                        sa[mi][ni], 0, 0, 0);
        }
#pragma unroll
        for (int mi = 0; mi < 4; ++mi)
#pragma unroll
            for (int ni = 0; ni < 2; ++ni)
#pragma unroll
                for (int r = 0; r < 4; ++r)
                    rmax[mi * 4 + r] = fmaxf(rmax[mi * 4 + r], sa[mi][ni][r]);
    }
#pragma unroll
    for (int i = 0; i < 16; ++i) {
        float v = rmax[i];
#pragma unroll
        for (int d = 1; d < 16; d <<= 1) v = fmaxf(v, __shfl_xor(v, d, 64));
        rmax[i] = v;
    }
    if (l15 == 0) {
#pragma unroll
        for (int mi = 0; mi < 4; ++mi)
#pragma unroll
            for (int r = 0; r < 4; ++r)
                red[wn][wm * 64 + mi * 16 + quad * 4 + r] = rmax[mi * 4 + r];
    }
    __syncthreads();
    if (t < 128) mrow[t] = fmaxf(red[0][t], red[1][t]);
    __syncthreads();

    // ---------------- pass 2: p = s3(scale*(dot - max)); Sum p; P @ V ----------
    float rsum[16];
#pragma unroll
    for (int i = 0; i < 16; ++i) rsum[i] = 0.f;
    floatx4 oacc[2][4];
#pragma unroll
    for (int i = 0; i < 2; ++i)
#pragma unroll
        for (int j = 0; j < 4; ++j) oacc[i][j] = zf;

    for (int kt = 0; kt < 2048; kt += 64) {
        __syncthreads();
#pragma unroll
        for (int it = 0; it < 2; ++it) {
            int cc = it * 256 + t;
            *(half8*)&Ks[cc * 8] = *(const half8*)&Kp[kt * 64 + cc * 8];
            int r = cc >> 3, c8 = cc & 7;
            *(half8*)&VTs[r * 64 + c8 * 8] =
                *(const half8*)&VTp[(size_t)r * 2048 + kt + c8 * 8];
        }
        __syncthreads();
        floatx4 sa[4][2];
#pragma unroll
        for (int mi = 0; mi < 4; ++mi) { sa[mi][0] = zf; sa[mi][1] = zf; }
#pragma unroll
        for (int kk = 0; kk < 2; ++kk) {
            half8 af[4], bfr[2];
#pragma unroll
            for (int mi = 0; mi < 4; ++mi)
                af[mi] = *(const half8*)&Qs[(wm * 64 + mi * 16 + l15) * 64 + kk * 32 + quad * 8];
#pragma unroll
            for (int ni = 0; ni < 2; ++ni)
                bfr[ni] = *(const half8*)&Ks[(wn * 32 + ni * 16 + l15) * 64 + kk * 32 + quad * 8];
#pragma unroll
            for (int mi = 0; mi < 4; ++mi)
#pragma unroll
                for (int ni = 0; ni < 2; ++ni)
                    sa[mi][ni] = __builtin_amdgcn_mfma_f32_16x16x32_f16(af[mi], bfr[ni],
                                                                        sa[mi][ni], 0, 0, 0);
        }
#pragma unroll
        for (int mi = 0; mi < 4; ++mi) {
            int rowb = wm * 64 + mi * 16 + quad * 4;
            float mv[4];
#pragma unroll
            for (int r = 0; r < 4; ++r) mv[r] = mrow[rowb + r];
#pragma unroll
            for (int ni = 0; ni < 2; ++ni) {
#pragma unroll
                for (int r = 0; r < 4; ++r) {
                    float x = 0.125f * (sa[mi][ni][r] - mv[r]);
                    float p = s3fn(x);
                    rsum[mi * 4 + r] += p;
                    Ps[(rowb + r) * 64 + wn * 32 + ni * 16 + l15] = (_Float16)p;
                }
            }
        }
        __syncthreads();
#pragma unroll
        for (int kk = 0; kk < 2; ++kk) {
            half8 pf[2], vf[4];
#pragma unroll
            for (int mi2 = 0; mi2 < 2; ++mi2)
                pf[mi2] = *(const half8*)&Ps[(w * 32 + mi2 * 16 + l15) * 64 + kk * 32 + quad * 8];
#pragma unroll
            for (int di = 0; di < 4; ++di)
                vf[di] = *(const half8*)&VTs[(di * 16 + l15) * 64 + kk * 32 + quad * 8];
#pragma unroll
            for (int mi2 = 0; mi2 < 2; ++mi2)
#pragma unroll
                for (int di = 0; di < 4; ++di)
                    oacc[mi2][di] = __builtin_amdgcn_mfma_f32_16x16x32_f16(pf[mi2], vf[di],
                                                                           oacc[mi2][di], 0, 0, 0);
        }
    }

#pragma unroll
    for (int i = 0; i < 16; ++i) {
        float v = rsum[i];
#pragma unroll
        for (int d = 1; d < 16; d <<= 1) v += __shfl_xor(v, d, 64);
        rsum[i] = v;
    }
    if (l15 == 0) {
#pragma unroll
        for (int mi = 0; mi < 4; ++mi)
#pragma unroll
            for (int r = 0; r < 4; ++r)
                red[wn][wm * 64 + mi * 16 + quad * 4 + r] = rsum[mi * 4 + r];
    }
    __syncthreads();
    if (t < 128) srow[t] = red[0][t] + red[1][t];
    __syncthreads();

    // epilogue: out[b, q0+row, h*64 + d] = oacc / srow   (fp16 intermediate buffer)
    _Float16* Op = out + (size_t)(b * 2048 + q0) * 1024 + h * 64;
#pragma unroll
    for (int mi2 = 0; mi2 < 2; ++mi2) {
#pragma unroll
        for (int r = 0; r < 4; ++r) {
            int row = w * 32 + mi2 * 16 + quad * 4 + r;
            float inv = 1.0f / srow[row];
#pragma unroll
            for (int di = 0; di < 4; ++di) {
                Op[(size_t)row * 1024 + di * 16 + l15] = (_Float16)(oacc[mi2][di][r] * inv);
            }
        }
    }
}

// ---------------- launch ---------------------------------------------------------
extern "C" void kernel_launch(void* const* d_in, const int* in_sizes, int n_in,
                              void* d_out, int out_size, void* d_ws, size_t ws_size,
                              hipStream_t stream) {
    const float* x_f = (const float*)d_in[0];     // [2,2048,1024] fp32
    const float* wqkv_f = (const float*)d_in[1];  // [3072,1024] fp32
    const float* wout_f = (const float*)d_in[2];  // [1024,1024] fp32
    const float* bias_f = (const float*)d_in[3];  // [1024] fp32

    // workspace: 32 MB total
    char* ws = (char*)d_ws;
    _Float16* qh = (_Float16*)(ws);                   // [32][2048][64] fp16, 8 MB
    _Float16* kh = (_Float16*)(ws + 8388608);         // [32][2048][64] fp16, 8 MB
    _Float16* vth = (_Float16*)(ws + 16777216);       // [32][64][2048] fp16, 8 MB
    _Float16* aoh = (_Float16*)(ws + 25165824);       // [4096][1024]  fp16, 8 MB

    gemm_qkv<<<dim3(24, 32), 256, 0, stream>>>(x_f, wqkv_f, qh, kh, vth);
    attn_kernel<<<dim3(16, 32), 256, 0, stream>>>(qh, kh, vth, aoh);
    gemm_out<<<dim3(8, 32), 256, 0, stream>>>(aoh, wout_f, (float*)d_out, bias_f);
}

// Round 4
// 261.275 us; speedup vs baseline: 1.3410x; 1.3410x over previous
//
#include <hip/hip_runtime.h>

typedef _Float16 half8 __attribute__((ext_vector_type(8)));
typedef _Float16 half4 __attribute__((ext_vector_type(4)));
typedef float floatx4 __attribute__((ext_vector_type(4)));

// ---------------- GEMM1: qkv = x @ w_qkv^T, split epilogue to head-major q/k/vt --
// M=4096, N=3072, K=1024. 128x128 tile, BK=32, 256 threads. LDS stride 40 (pad).
__global__ __launch_bounds__(256) void gemm_qkv(const float* __restrict__ X,
                                                const float* __restrict__ W,
                                                _Float16* __restrict__ qh,
                                                _Float16* __restrict__ kh,
                                                _Float16* __restrict__ vth) {
    const int K = 1024;
    __shared__ _Float16 As[128 * 40];
    __shared__ _Float16 Bs[128 * 40];
    const int t = threadIdx.x;
    const int lane = t & 63, w = t >> 6;
    const int l15 = lane & 15, quad = lane >> 4;
    const int wm = w >> 1, wn = w & 1;
    const int m0 = blockIdx.y * 128, n0 = blockIdx.x * 128;

    floatx4 acc[4][4];
    const floatx4 zf = {0.f, 0.f, 0.f, 0.f};
#pragma unroll
    for (int i = 0; i < 4; ++i)
#pragma unroll
        for (int j = 0; j < 4; ++j) acc[i][j] = zf;

    for (int kt = 0; kt < K; kt += 32) {
        __syncthreads();
#pragma unroll
        for (int it = 0; it < 4; ++it) {
            int cc = it * 256 + t;          // 1024 chunks of 4 floats
            int row = cc >> 3, c4 = cc & 7;
            floatx4 xv = *(const floatx4*)&X[(size_t)(m0 + row) * K + kt + c4 * 4];
            floatx4 wv = *(const floatx4*)&W[(size_t)(n0 + row) * K + kt + c4 * 4];
            half4 xh, wh;
#pragma unroll
            for (int j = 0; j < 4; ++j) { xh[j] = (_Float16)xv[j]; wh[j] = (_Float16)wv[j]; }
            *(half4*)&As[row * 40 + c4 * 4] = xh;
            *(half4*)&Bs[row * 40 + c4 * 4] = wh;
        }
        __syncthreads();
        half8 af[4], bfr[4];
#pragma unroll
        for (int i = 0; i < 4; ++i)
            af[i] = *(const half8*)&As[(wm * 64 + i * 16 + l15) * 40 + quad * 8];
#pragma unroll
        for (int i = 0; i < 4; ++i)
            bfr[i] = *(const half8*)&Bs[(wn * 64 + i * 16 + l15) * 40 + quad * 8];
#pragma unroll
        for (int mi = 0; mi < 4; ++mi)
#pragma unroll
            for (int ni = 0; ni < 4; ++ni)
                acc[mi][ni] = __builtin_amdgcn_mfma_f32_16x16x32_f16(af[mi], bfr[ni],
                                                                     acc[mi][ni], 0, 0, 0);
    }

#pragma unroll
    for (int mi = 0; mi < 4; ++mi) {
#pragma unroll
        for (int ni = 0; ni < 4; ++ni) {
            int col = n0 + wn * 64 + ni * 16 + l15;
#pragma unroll
            for (int r = 0; r < 4; ++r) {
                int row = m0 + wm * 64 + mi * 16 + quad * 4 + r;
                int b = row >> 11, s = row & 2047;
                _Float16 hv = (_Float16)acc[mi][ni][r];
                if (col < 1024) {
                    qh[(size_t)((b << 4) | (col >> 6)) * 131072 + s * 64 + (col & 63)] = hv;
                } else if (col < 2048) {
                    int c = col - 1024;
                    kh[(size_t)((b << 4) | (c >> 6)) * 131072 + s * 64 + (c & 63)] = hv;
                } else {
                    int c = col - 2048;
                    vth[(size_t)((b << 4) | (c >> 6)) * 131072 + (c & 63) * 2048 + s] = hv;
                }
            }
        }
    }
}

// ---------------- GEMM2: out = aoh @ w_out^T + b_out -> fp32 ---------------------
__global__ __launch_bounds__(256) void gemm_out(const _Float16* __restrict__ A,
                                                const float* __restrict__ W,
                                                float* __restrict__ C,
                                                const float* __restrict__ bias) {
    const int K = 1024, N = 1024;
    __shared__ _Float16 As[128 * 40];
    __shared__ _Float16 Bs[128 * 40];
    const int t = threadIdx.x;
    const int lane = t & 63, w = t >> 6;
    const int l15 = lane & 15, quad = lane >> 4;
    const int wm = w >> 1, wn = w & 1;
    const int m0 = blockIdx.y * 128, n0 = blockIdx.x * 128;

    floatx4 acc[4][4];
    const floatx4 zf = {0.f, 0.f, 0.f, 0.f};
#pragma unroll
    for (int i = 0; i < 4; ++i)
#pragma unroll
        for (int j = 0; j < 4; ++j) acc[i][j] = zf;

    for (int kt = 0; kt < K; kt += 32) {
        __syncthreads();
#pragma unroll
        for (int it = 0; it < 2; ++it) {        // A: fp16 source
            int cc = it * 256 + t;
            int row = cc >> 2, kc = cc & 3;
            *(half8*)&As[row * 40 + kc * 8] =
                *(const half8*)&A[(size_t)(m0 + row) * K + kt + kc * 8];
        }
#pragma unroll
        for (int it = 0; it < 4; ++it) {        // B: fp32 source
            int cc = it * 256 + t;
            int row = cc >> 3, c4 = cc & 7;
            floatx4 wv = *(const floatx4*)&W[(size_t)(n0 + row) * K + kt + c4 * 4];
            half4 wh;
#pragma unroll
            for (int j = 0; j < 4; ++j) wh[j] = (_Float16)wv[j];
            *(half4*)&Bs[row * 40 + c4 * 4] = wh;
        }
        __syncthreads();
        half8 af[4], bfr[4];
#pragma unroll
        for (int i = 0; i < 4; ++i)
            af[i] = *(const half8*)&As[(wm * 64 + i * 16 + l15) * 40 + quad * 8];
#pragma unroll
        for (int i = 0; i < 4; ++i)
            bfr[i] = *(const half8*)&Bs[(wn * 64 + i * 16 + l15) * 40 + quad * 8];
#pragma unroll
        for (int mi = 0; mi < 4; ++mi)
#pragma unroll
            for (int ni = 0; ni < 4; ++ni)
                acc[mi][ni] = __builtin_amdgcn_mfma_f32_16x16x32_f16(af[mi], bfr[ni],
                                                                     acc[mi][ni], 0, 0, 0);
    }

#pragma unroll
    for (int mi = 0; mi < 4; ++mi) {
#pragma unroll
        for (int ni = 0; ni < 4; ++ni) {
            int col = n0 + wn * 64 + ni * 16 + l15;
            float bv = bias[col];
#pragma unroll
            for (int r = 0; r < 4; ++r) {
                int row = m0 + wm * 64 + mi * 16 + quad * 4 + r;
                C[(size_t)row * N + col] = acc[mi][ni][r] + bv;
            }
        }
    }
}

// pos(a) = 1 + a + a^2/2 + a^3/6  (Horner, 3 fma)
__device__ inline float s3pos(float a) {
    float h = fmaf(a, 0.16666667f, 0.5f);
    h = fmaf(a, h, 1.0f);
    return fmaf(a, h, 1.0f);
}

// ---------------- fused two-pass stablemax attention (S^T form) ------------------
// grid (S/128, B*H), 256 threads. Computes S^T = K·Q^T so q lives on lane&15:
// row reductions are wave-local, and s3(P) feeds the PV mfma straight from
// registers via a permuted key order (key = 32c + 16(j>>2) + 4*quad + (j&3)).
__global__ __launch_bounds__(256) void attn_kernel(const _Float16* __restrict__ qh,
                                                   const _Float16* __restrict__ kh,
                                                   const _Float16* __restrict__ vth,
                                                   _Float16* __restrict__ out) {
    __shared__ _Float16 Qs[128 * 72];   // 18 KB, padded stride 72 (2-way banks)
    __shared__ _Float16 Ks[64 * 72];    // 9 KB
    __shared__ _Float16 VTs[64 * 72];   // 9 KB  VT[d][key]

    const int t = threadIdx.x;
    const int lane = t & 63, w = t >> 6;
    const int l15 = lane & 15, quad = lane >> 4;
    const int q0 = blockIdx.x * 128;
    const int bh = blockIdx.y;
    const int b = bh >> 4, h = bh & 15;

    const _Float16* Qp = qh + (size_t)bh * 131072 + q0 * 64;
    const _Float16* Kp = kh + (size_t)bh * 131072;
    const _Float16* VTp = vth + (size_t)bh * 131072;

    const floatx4 zf = {0.f, 0.f, 0.f, 0.f};

    // load Q tile: 128 rows x 64 cols into padded LDS
#pragma unroll
    for (int it = 0; it < 4; ++it) {
        int cc = it * 256 + t;
        int r = cc >> 3, c8 = cc & 7;
        *(half8*)&Qs[r * 72 + c8 * 8] = *(const half8*)&Qp[cc * 8];
    }

    // wave w owns q = w*32 + n*16 + l15 (n=0,1); keys partitioned over quads.
    // ---------------- pass 1: row max over keys -----------------------------
    float rmax[2] = {-1.0e30f, -1.0e30f};

    for (int kt = 0; kt < 2048; kt += 64) {
        __syncthreads();
#pragma unroll
        for (int it = 0; it < 2; ++it) {
            int cc = it * 256 + t;
            int r = cc >> 3, c8 = cc & 7;
            *(half8*)&Ks[r * 72 + c8 * 8] = *(const half8*)&Kp[kt * 64 + cc * 8];
        }
        __syncthreads();
        floatx4 sa[4][2];
#pragma unroll
        for (int T = 0; T < 4; ++T) { sa[T][0] = zf; sa[T][1] = zf; }
#pragma unroll
        for (int kk = 0; kk < 2; ++kk) {
            half8 kf[4], qf[2];
#pragma unroll
            for (int T = 0; T < 4; ++T)
                kf[T] = *(const half8*)&Ks[(T * 16 + l15) * 72 + kk * 32 + quad * 8];
#pragma unroll
            for (int n = 0; n < 2; ++n)
                qf[n] = *(const half8*)&Qs[(w * 32 + n * 16 + l15) * 72 + kk * 32 + quad * 8];
#pragma unroll
            for (int T = 0; T < 4; ++T)
#pragma unroll
                for (int n = 0; n < 2; ++n)
                    sa[T][n] = __builtin_amdgcn_mfma_f32_16x16x32_f16(kf[T], qf[n],
                                                                      sa[T][n], 0, 0, 0);
        }
#pragma unroll
        for (int T = 0; T < 4; ++T)
#pragma unroll
            for (int n = 0; n < 2; ++n)
#pragma unroll
                for (int r = 0; r < 4; ++r)
                    rmax[n] = fmaxf(rmax[n], sa[T][n][r]);
    }
    // combine across quads (same l15 = same q)
#pragma unroll
    for (int n = 0; n < 2; ++n) {
        rmax[n] = fmaxf(rmax[n], __shfl_xor(rmax[n], 16, 64));
        rmax[n] = fmaxf(rmax[n], __shfl_xor(rmax[n], 32, 64));
    }
    const float xm0 = -0.125f * rmax[0], xm1 = -0.125f * rmax[1];

    // ---------------- pass 2: p = s3(0.125*(dot - max)); Sum p; P·V ----------
    float rsum[2] = {0.f, 0.f};
    floatx4 oacc[4][2];   // O^T: m-tile d (4) x n (2)
#pragma unroll
    for (int i = 0; i < 4; ++i) { oacc[i][0] = zf; oacc[i][1] = zf; }

    for (int kt = 0; kt < 2048; kt += 64) {
        __syncthreads();
#pragma unroll
        for (int it = 0; it < 2; ++it) {
            int cc = it * 256 + t;
            int r = cc >> 3, c8 = cc & 7;
            *(half8*)&Ks[r * 72 + c8 * 8] = *(const half8*)&Kp[kt * 64 + cc * 8];
            *(half8*)&VTs[r * 72 + c8 * 8] =
                *(const half8*)&VTp[(size_t)r * 2048 + kt + c8 * 8];
        }
        __syncthreads();
        floatx4 sa[4][2];
#pragma unroll
        for (int T = 0; T < 4; ++T) { sa[T][0] = zf; sa[T][1] = zf; }
#pragma unroll
        for (int kk = 0; kk < 2; ++kk) {
            half8 kf[4], qf[2];
#pragma unroll
            for (int T = 0; T < 4; ++T)
                kf[T] = *(const half8*)&Ks[(T * 16 + l15) * 72 + kk * 32 + quad * 8];
#pragma unroll
            for (int n = 0; n < 2; ++n)
                qf[n] = *(const half8*)&Qs[(w * 32 + n * 16 + l15) * 72 + kk * 32 + quad * 8];
#pragma unroll
            for (int T = 0; T < 4; ++T)
#pragma unroll
                for (int n = 0; n < 2; ++n)
                    sa[T][n] = __builtin_amdgcn_mfma_f32_16x16x32_f16(kf[T], qf[n],
                                                                      sa[T][n], 0, 0, 0);
        }
        // s3 in-register; x <= 0 always (same-mfma recompute) so s3 = rcp(pos(|x|))
        half8 pb[2][2];   // [n][c] PV B-operand fragments
#pragma unroll
        for (int n = 0; n < 2; ++n) {
            float xm = n ? xm1 : xm0;
            float p[4][4];
#pragma unroll
            for (int T = 0; T < 4; ++T)
#pragma unroll
                for (int r = 0; r < 4; ++r) {
                    float x = fmaf(sa[T][n][r], 0.125f, xm);
                    float pv = __builtin_amdgcn_rcpf(s3pos(fabsf(x)));
                    p[T][r] = pv;
                    rsum[n] += pv;
                }
#pragma unroll
            for (int c = 0; c < 2; ++c) {
                half8 v;
#pragma unroll
                for (int j = 0; j < 8; ++j)
                    v[j] = (_Float16)p[2 * c + (j >> 2)][j & 3];
                pb[n][c] = v;
            }
        }
        // PV: O^T[d][q] += VT[d][key] * P[q][key], permuted key order
#pragma unroll
        for (int c = 0; c < 2; ++c) {
            half8 vf[4];
#pragma unroll
            for (int di = 0; di < 4; ++di) {
                half4 lo = *(const half4*)&VTs[(di * 16 + l15) * 72 + c * 32 + 4 * quad];
                half4 hi = *(const half4*)&VTs[(di * 16 + l15) * 72 + c * 32 + 16 + 4 * quad];
                half8 vv;
#pragma unroll
                for (int j = 0; j < 4; ++j) { vv[j] = lo[j]; vv[j + 4] = hi[j]; }
                vf[di] = vv;
            }
#pragma unroll
            for (int di = 0; di < 4; ++di)
#pragma unroll
                for (int n = 0; n < 2; ++n)
                    oacc[di][n] = __builtin_amdgcn_mfma_f32_16x16x32_f16(vf[di], pb[n][c],
                                                                         oacc[di][n], 0, 0, 0);
        }
    }

    // row sums across quads
#pragma unroll
    for (int n = 0; n < 2; ++n) {
        rsum[n] += __shfl_xor(rsum[n], 16, 64);
        rsum[n] += __shfl_xor(rsum[n], 32, 64);
    }
    const float inv0 = 1.0f / rsum[0], inv1 = 1.0f / rsum[1];

    // stage O (q-major) into LDS (reuse Qs) for coalesced global write
    __syncthreads();
    _Float16* Os = Qs;
#pragma unroll
    for (int di = 0; di < 4; ++di) {
#pragma unroll
        for (int n = 0; n < 2; ++n) {
            float inv = n ? inv1 : inv0;
            half4 hv;
#pragma unroll
            for (int r = 0; r < 4; ++r) hv[r] = (_Float16)(oacc[di][n][r] * inv);
            *(half4*)&Os[(w * 32 + n * 16 + l15) * 72 + di * 16 + quad * 4] = hv;
        }
    }
    __syncthreads();
    _Float16* Op = out + (size_t)(b * 2048 + q0) * 1024 + h * 64;
#pragma unroll
    for (int it = 0; it < 4; ++it) {
        int cc = it * 256 + t;
        int r = cc >> 3, c8 = cc & 7;
        *(half8*)&Op[(size_t)r * 1024 + c8 * 8] = *(const half8*)&Os[r * 72 + c8 * 8];
    }
}

// ---------------- launch ---------------------------------------------------------
extern "C" void kernel_launch(void* const* d_in, const int* in_sizes, int n_in,
                              void* d_out, int out_size, void* d_ws, size_t ws_size,
                              hipStream_t stream) {
    const float* x_f = (const float*)d_in[0];     // [2,2048,1024] fp32
    const float* wqkv_f = (const float*)d_in[1];  // [3072,1024] fp32
    const float* wout_f = (const float*)d_in[2];  // [1024,1024] fp32
    const float* bias_f = (const float*)d_in[3];  // [1024] fp32

    // workspace: 32 MB total
    char* ws = (char*)d_ws;
    _Float16* qh = (_Float16*)(ws);                   // [32][2048][64] fp16, 8 MB
    _Float16* kh = (_Float16*)(ws + 8388608);         // [32][2048][64] fp16, 8 MB
    _Float16* vth = (_Float16*)(ws + 16777216);       // [32][64][2048] fp16, 8 MB
    _Float16* aoh = (_Float16*)(ws + 25165824);       // [4096][1024]  fp16, 8 MB

    gemm_qkv<<<dim3(24, 32), 256, 0, stream>>>(x_f, wqkv_f, qh, kh, vth);
    attn_kernel<<<dim3(16, 32), 256, 0, stream>>>(qh, kh, vth, aoh);
    gemm_out<<<dim3(8, 32), 256, 0, stream>>>(aoh, wout_f, (float*)d_out, bias_f);
}

// Round 5
// 260.214 us; speedup vs baseline: 1.3465x; 1.0041x over previous
//
#include <hip/hip_runtime.h>

typedef _Float16 half8 __attribute__((ext_vector_type(8)));
typedef _Float16 half4 __attribute__((ext_vector_type(4)));
typedef float floatx4 __attribute__((ext_vector_type(4)));

// ---------------- GEMM1: qkv = x @ w_qkv^T, split epilogue to head-major q/k/vt --
// M=4096, N=3072, K=1024. 128x128 tile, BK=32, 256 threads. LDS stride 40 (pad).
__global__ __launch_bounds__(256) void gemm_qkv(const float* __restrict__ X,
                                                const float* __restrict__ W,
                                                _Float16* __restrict__ qh,
                                                _Float16* __restrict__ kh,
                                                _Float16* __restrict__ vth) {
    const int K = 1024;
    __shared__ _Float16 As[128 * 40];
    __shared__ _Float16 Bs[128 * 40];
    const int t = threadIdx.x;
    const int lane = t & 63, w = t >> 6;
    const int l15 = lane & 15, quad = lane >> 4;
    const int wm = w >> 1, wn = w & 1;
    const int m0 = blockIdx.y * 128, n0 = blockIdx.x * 128;

    floatx4 acc[4][4];
    const floatx4 zf = {0.f, 0.f, 0.f, 0.f};
#pragma unroll
    for (int i = 0; i < 4; ++i)
#pragma unroll
        for (int j = 0; j < 4; ++j) acc[i][j] = zf;

    for (int kt = 0; kt < K; kt += 32) {
        __syncthreads();
#pragma unroll
        for (int it = 0; it < 4; ++it) {
            int cc = it * 256 + t;          // 1024 chunks of 4 floats
            int row = cc >> 3, c4 = cc & 7;
            floatx4 xv = *(const floatx4*)&X[(size_t)(m0 + row) * K + kt + c4 * 4];
            floatx4 wv = *(const floatx4*)&W[(size_t)(n0 + row) * K + kt + c4 * 4];
            half4 xh, wh;
#pragma unroll
            for (int j = 0; j < 4; ++j) { xh[j] = (_Float16)xv[j]; wh[j] = (_Float16)wv[j]; }
            *(half4*)&As[row * 40 + c4 * 4] = xh;
            *(half4*)&Bs[row * 40 + c4 * 4] = wh;
        }
        __syncthreads();
        half8 af[4], bfr[4];
#pragma unroll
        for (int i = 0; i < 4; ++i)
            af[i] = *(const half8*)&As[(wm * 64 + i * 16 + l15) * 40 + quad * 8];
#pragma unroll
        for (int i = 0; i < 4; ++i)
            bfr[i] = *(const half8*)&Bs[(wn * 64 + i * 16 + l15) * 40 + quad * 8];
#pragma unroll
        for (int mi = 0; mi < 4; ++mi)
#pragma unroll
            for (int ni = 0; ni < 4; ++ni)
                acc[mi][ni] = __builtin_amdgcn_mfma_f32_16x16x32_f16(af[mi], bfr[ni],
                                                                     acc[mi][ni], 0, 0, 0);
    }

#pragma unroll
    for (int mi = 0; mi < 4; ++mi) {
#pragma unroll
        for (int ni = 0; ni < 4; ++ni) {
            int col = n0 + wn * 64 + ni * 16 + l15;
#pragma unroll
            for (int r = 0; r < 4; ++r) {
                int row = m0 + wm * 64 + mi * 16 + quad * 4 + r;
                int b = row >> 11, s = row & 2047;
                _Float16 hv = (_Float16)acc[mi][ni][r];
                if (col < 1024) {
                    qh[(size_t)((b << 4) | (col >> 6)) * 131072 + s * 64 + (col & 63)] = hv;
                } else if (col < 2048) {
                    int c = col - 1024;
                    kh[(size_t)((b << 4) | (c >> 6)) * 131072 + s * 64 + (c & 63)] = hv;
                } else {
                    int c = col - 2048;
                    vth[(size_t)((b << 4) | (c >> 6)) * 131072 + (c & 63) * 2048 + s] = hv;
                }
            }
        }
    }
}

// ---------------- GEMM2: out = aoh @ w_out^T + b_out -> fp32 ---------------------
// 64x128 tile (grid 8x64 = 512 blocks -> 2 blocks/CU), BK=32, 256 threads.
__global__ __launch_bounds__(256) void gemm_out(const _Float16* __restrict__ A,
                                                const float* __restrict__ W,
                                                float* __restrict__ C,
                                                const float* __restrict__ bias) {
    const int K = 1024, N = 1024;
    __shared__ _Float16 As[64 * 40];
    __shared__ _Float16 Bs[128 * 40];
    const int t = threadIdx.x;
    const int lane = t & 63, w = t >> 6;
    const int l15 = lane & 15, quad = lane >> 4;
    const int wm = w >> 1, wn = w & 1;   // wave: rows wm*32.., cols wn*64..
    const int m0 = blockIdx.y * 64, n0 = blockIdx.x * 128;

    floatx4 acc[2][4];
    const floatx4 zf = {0.f, 0.f, 0.f, 0.f};
#pragma unroll
    for (int i = 0; i < 2; ++i)
#pragma unroll
        for (int j = 0; j < 4; ++j) acc[i][j] = zf;

    for (int kt = 0; kt < K; kt += 32) {
        __syncthreads();
        {   // A: fp16 source, 64x32 = 256 chunks of 8
            int row = t >> 2, kc = t & 3;
            *(half8*)&As[row * 40 + kc * 8] =
                *(const half8*)&A[(size_t)(m0 + row) * K + kt + kc * 8];
        }
#pragma unroll
        for (int it = 0; it < 4; ++it) {        // B: fp32 source, 1024 chunks of 4
            int cc = it * 256 + t;
            int row = cc >> 3, c4 = cc & 7;
            floatx4 wv = *(const floatx4*)&W[(size_t)(n0 + row) * K + kt + c4 * 4];
            half4 wh;
#pragma unroll
            for (int j = 0; j < 4; ++j) wh[j] = (_Float16)wv[j];
            *(half4*)&Bs[row * 40 + c4 * 4] = wh;
        }
        __syncthreads();
        half8 af[2], bfr[4];
#pragma unroll
        for (int i = 0; i < 2; ++i)
            af[i] = *(const half8*)&As[(wm * 32 + i * 16 + l15) * 40 + quad * 8];
#pragma unroll
        for (int i = 0; i < 4; ++i)
            bfr[i] = *(const half8*)&Bs[(wn * 64 + i * 16 + l15) * 40 + quad * 8];
#pragma unroll
        for (int mi = 0; mi < 2; ++mi)
#pragma unroll
            for (int ni = 0; ni < 4; ++ni)
                acc[mi][ni] = __builtin_amdgcn_mfma_f32_16x16x32_f16(af[mi], bfr[ni],
                                                                     acc[mi][ni], 0, 0, 0);
    }

#pragma unroll
    for (int mi = 0; mi < 2; ++mi) {
#pragma unroll
        for (int ni = 0; ni < 4; ++ni) {
            int col = n0 + wn * 64 + ni * 16 + l15;
            float bv = bias[col];
#pragma unroll
            for (int r = 0; r < 4; ++r) {
                int row = m0 + wm * 32 + mi * 16 + quad * 4 + r;
                C[(size_t)row * N + col] = acc[mi][ni][r] + bv;
            }
        }
    }
}

// pos(a) = 1 + a + a^2/2 + a^3/6  (Horner, 3 fma)
__device__ inline float s3pos(float a) {
    float h = fmaf(a, 0.16666667f, 0.5f);
    h = fmaf(a, h, 1.0f);
    return fmaf(a, h, 1.0f);
}

// ---------------- fused two-pass stablemax attention (S^T form, 8 waves) ---------
// grid (S/128, B*H), 512 threads. Wave w owns q rows w*16+l15; keys over quads.
// key permutation for PV: key(kappa = quad*8+j) = c*32 + (j>>2)*16 + quad*4 + (j&3)
// makes each lane's PV B-operand exactly its own s3 outputs (P never hits LDS).
__global__ __launch_bounds__(512) void attn_kernel(const _Float16* __restrict__ qh,
                                                   const _Float16* __restrict__ kh,
                                                   const _Float16* __restrict__ vth,
                                                   _Float16* __restrict__ out) {
    __shared__ _Float16 Qs[128 * 72];   // 18 KB, padded stride 72
    __shared__ _Float16 Ks[64 * 72];    // 9 KB
    __shared__ _Float16 VTs[64 * 72];   // 9 KB  VT[d][key]

    const int t = threadIdx.x;
    const int lane = t & 63, w = t >> 6;
    const int l15 = lane & 15, quad = lane >> 4;
    const int q0 = blockIdx.x * 128;
    const int bh = blockIdx.y;
    const int b = bh >> 4, h = bh & 15;

    const _Float16* Qp = qh + (size_t)bh * 131072 + q0 * 64;
    const _Float16* Kp = kh + (size_t)bh * 131072;
    const _Float16* VTp = vth + (size_t)bh * 131072;

    const floatx4 zf = {0.f, 0.f, 0.f, 0.f};

    // load Q tile: 128 rows x 64 cols into padded LDS (1024 chunks / 512 threads)
#pragma unroll
    for (int it = 0; it < 2; ++it) {
        int cc = it * 512 + t;
        int r = cc >> 3, c8 = cc & 7;
        *(half8*)&Qs[r * 72 + c8 * 8] = *(const half8*)&Qp[cc * 8];
    }

    const int qrow = w * 16 + l15;   // this lane's q row (all its scores share it)

    // ---------------- pass 1: row max over keys -----------------------------
    float rmax = -1.0e30f;

    for (int kt = 0; kt < 2048; kt += 64) {
        __syncthreads();
        {   // K tile: 64x64 = 512 chunks of 8, one per thread
            int r = t >> 3, c8 = t & 7;
            *(half8*)&Ks[r * 72 + c8 * 8] = *(const half8*)&Kp[kt * 64 + t * 8];
        }
        __syncthreads();
        floatx4 sa[4];
#pragma unroll
        for (int T = 0; T < 4; ++T) sa[T] = zf;
#pragma unroll
        for (int kk = 0; kk < 2; ++kk) {
            half8 qf = *(const half8*)&Qs[qrow * 72 + kk * 32 + quad * 8];
            half8 kf[4];
#pragma unroll
            for (int T = 0; T < 4; ++T)
                kf[T] = *(const half8*)&Ks[(T * 16 + l15) * 72 + kk * 32 + quad * 8];
#pragma unroll
            for (int T = 0; T < 4; ++T)
                sa[T] = __builtin_amdgcn_mfma_f32_16x16x32_f16(kf[T], qf, sa[T], 0, 0, 0);
        }
#pragma unroll
        for (int T = 0; T < 4; ++T)
#pragma unroll
            for (int r = 0; r < 4; ++r)
                rmax = fmaxf(rmax, sa[T][r]);
    }
    // combine across quads (same l15 = same q)
    rmax = fmaxf(rmax, __shfl_xor(rmax, 16, 64));
    rmax = fmaxf(rmax, __shfl_xor(rmax, 32, 64));
    const float xm = -0.125f * rmax;

    // ---------------- pass 2: p = s3(0.125*dot + xm); Sum p; P·V -------------
    float rsum = 0.f;
    floatx4 oacc[4];   // O^T: d-tiles
#pragma unroll
    for (int i = 0; i < 4; ++i) oacc[i] = zf;

    for (int kt = 0; kt < 2048; kt += 64) {
        __syncthreads();
        {
            int r = t >> 3, c8 = t & 7;
            *(half8*)&Ks[r * 72 + c8 * 8] = *(const half8*)&Kp[kt * 64 + t * 8];
            *(half8*)&VTs[r * 72 + c8 * 8] =
                *(const half8*)&VTp[(size_t)r * 2048 + kt + c8 * 8];
        }
        __syncthreads();
        floatx4 sa[4];
#pragma unroll
        for (int T = 0; T < 4; ++T) sa[T] = zf;
#pragma unroll
        for (int kk = 0; kk < 2; ++kk) {
            half8 qf = *(const half8*)&Qs[qrow * 72 + kk * 32 + quad * 8];
            half8 kf[4];
#pragma unroll
            for (int T = 0; T < 4; ++T)
                kf[T] = *(const half8*)&Ks[(T * 16 + l15) * 72 + kk * 32 + quad * 8];
#pragma unroll
            for (int T = 0; T < 4; ++T)
                sa[T] = __builtin_amdgcn_mfma_f32_16x16x32_f16(kf[T], qf, sa[T], 0, 0, 0);
        }
        // s3 in-register; x <= 0 always (bit-identical recompute) -> s3 = rcp(pos(|x|))
        float p[4][4];
#pragma unroll
        for (int T = 0; T < 4; ++T)
#pragma unroll
            for (int r = 0; r < 4; ++r) {
                float x = fmaf(sa[T][r], 0.125f, xm);
                float pv = __builtin_amdgcn_rcpf(s3pos(fabsf(x)));
                p[T][r] = pv;
                rsum += pv;
            }
        // PV: O^T[d][q] += VT[d][key] * P[q][key], permuted key order
#pragma unroll
        for (int c = 0; c < 2; ++c) {
            half8 pb;
#pragma unroll
            for (int j = 0; j < 8; ++j)
                pb[j] = (_Float16)p[2 * c + (j >> 2)][j & 3];
            half8 vf[4];
#pragma unroll
            for (int di = 0; di < 4; ++di) {
                half4 lo = *(const half4*)&VTs[(di * 16 + l15) * 72 + c * 32 + 4 * quad];
                half4 hi = *(const half4*)&VTs[(di * 16 + l15) * 72 + c * 32 + 16 + 4 * quad];
                half8 vv;
#pragma unroll
                for (int j = 0; j < 4; ++j) { vv[j] = lo[j]; vv[j + 4] = hi[j]; }
                vf[di] = vv;
            }
#pragma unroll
            for (int di = 0; di < 4; ++di)
                oacc[di] = __builtin_amdgcn_mfma_f32_16x16x32_f16(vf[di], pb,
                                                                 oacc[di], 0, 0, 0);
        }
    }

    // row sums across quads
    rsum += __shfl_xor(rsum, 16, 64);
    rsum += __shfl_xor(rsum, 32, 64);
    const float inv = 1.0f / rsum;

    // stage O (q-major) into LDS (reuse Qs) for coalesced global write
    __syncthreads();
    _Float16* Os = Qs;
#pragma unroll
    for (int di = 0; di < 4; ++di) {
        half4 hv;
#pragma unroll
        for (int r = 0; r < 4; ++r) hv[r] = (_Float16)(oacc[di][r] * inv);
        *(half4*)&Os[qrow * 72 + di * 16 + quad * 4] = hv;
    }
    __syncthreads();
    _Float16* Op = out + (size_t)(b * 2048 + q0) * 1024 + h * 64;
#pragma unroll
    for (int it = 0; it < 2; ++it) {
        int cc = it * 512 + t;
        int r = cc >> 3, c8 = cc & 7;
        *(half8*)&Op[(size_t)r * 1024 + c8 * 8] = *(const half8*)&Os[r * 72 + c8 * 8];
    }
}

// ---------------- launch ---------------------------------------------------------
extern "C" void kernel_launch(void* const* d_in, const int* in_sizes, int n_in,
                              void* d_out, int out_size, void* d_ws, size_t ws_size,
                              hipStream_t stream) {
    const float* x_f = (const float*)d_in[0];     // [2,2048,1024] fp32
    const float* wqkv_f = (const float*)d_in[1];  // [3072,1024] fp32
    const float* wout_f = (const float*)d_in[2];  // [1024,1024] fp32
    const float* bias_f = (const float*)d_in[3];  // [1024] fp32

    // workspace: 32 MB total
    char* ws = (char*)d_ws;
    _Float16* qh = (_Float16*)(ws);                   // [32][2048][64] fp16, 8 MB
    _Float16* kh = (_Float16*)(ws + 8388608);         // [32][2048][64] fp16, 8 MB
    _Float16* vth = (_Float16*)(ws + 16777216);       // [32][64][2048] fp16, 8 MB
    _Float16* aoh = (_Float16*)(ws + 25165824);       // [4096][1024]  fp16, 8 MB

    gemm_qkv<<<dim3(24, 32), 256, 0, stream>>>(x_f, wqkv_f, qh, kh, vth);
    attn_kernel<<<dim3(16, 32), 512, 0, stream>>>(qh, kh, vth, aoh);
    gemm_out<<<dim3(8, 64), 256, 0, stream>>>(aoh, wout_f, (float*)d_out, bias_f);
}

// Round 6
// 234.767 us; speedup vs baseline: 1.4924x; 1.1084x over previous
//
#include <hip/hip_runtime.h>

typedef _Float16 half8 __attribute__((ext_vector_type(8)));
typedef _Float16 half4 __attribute__((ext_vector_type(4)));
typedef float floatx4 __attribute__((ext_vector_type(4)));

// ---------------- GEMM1: qkv = x @ w_qkv^T, split epilogue to head-major q/k/vt --
// M=4096, N=3072, K=1024. 128x128 tile, BK=32, 256 threads. LDS stride 40 (pad).
// Epilogue stages C through LDS (stride 68) so every global write is a b128.
__global__ __launch_bounds__(256) void gemm_qkv(const float* __restrict__ X,
                                                const float* __restrict__ W,
                                                _Float16* __restrict__ qh,
                                                _Float16* __restrict__ kh,
                                                _Float16* __restrict__ vth) {
    const int K = 1024;
    __shared__ _Float16 SH[128 * 40 * 2];   // As | Bs; reused as C-stage (128x68)
    _Float16* As = SH;
    _Float16* Bs = SH + 128 * 40;
    const int t = threadIdx.x;
    const int lane = t & 63, w = t >> 6;
    const int l15 = lane & 15, quad = lane >> 4;
    const int wm = w >> 1, wn = w & 1;
    const int m0 = blockIdx.y * 128, n0 = blockIdx.x * 128;

    floatx4 acc[4][4];
    const floatx4 zf = {0.f, 0.f, 0.f, 0.f};
#pragma unroll
    for (int i = 0; i < 4; ++i)
#pragma unroll
        for (int j = 0; j < 4; ++j) acc[i][j] = zf;

    for (int kt = 0; kt < K; kt += 32) {
        __syncthreads();
#pragma unroll
        for (int it = 0; it < 4; ++it) {
            int cc = it * 256 + t;          // 1024 chunks of 4 floats
            int row = cc >> 3, c4 = cc & 7;
            floatx4 xv = *(const floatx4*)&X[(size_t)(m0 + row) * K + kt + c4 * 4];
            floatx4 wv = *(const floatx4*)&W[(size_t)(n0 + row) * K + kt + c4 * 4];
            half4 xh, wh;
#pragma unroll
            for (int j = 0; j < 4; ++j) { xh[j] = (_Float16)xv[j]; wh[j] = (_Float16)wv[j]; }
            *(half4*)&As[row * 40 + c4 * 4] = xh;
            *(half4*)&Bs[row * 40 + c4 * 4] = wh;
        }
        __syncthreads();
        half8 af[4], bfr[4];
#pragma unroll
        for (int i = 0; i < 4; ++i)
            af[i] = *(const half8*)&As[(wm * 64 + i * 16 + l15) * 40 + quad * 8];
#pragma unroll
        for (int i = 0; i < 4; ++i)
            bfr[i] = *(const half8*)&Bs[(wn * 64 + i * 16 + l15) * 40 + quad * 8];
#pragma unroll
        for (int mi = 0; mi < 4; ++mi)
#pragma unroll
            for (int ni = 0; ni < 4; ++ni)
                acc[mi][ni] = __builtin_amdgcn_mfma_f32_16x16x32_f16(af[mi], bfr[ni],
                                                                     acc[mi][ni], 0, 0, 0);
    }

    // ---- epilogue: two 128x64 col-halves staged through LDS, coalesced writes ----
    const int b = m0 >> 11, s0 = m0 & 2047;
#pragma unroll
    for (int hf = 0; hf < 2; ++hf) {
        __syncthreads();
        if (wn == hf) {
#pragma unroll
            for (int mi = 0; mi < 4; ++mi)
#pragma unroll
                for (int ni = 0; ni < 4; ++ni)
#pragma unroll
                    for (int r = 0; r < 4; ++r)
                        SH[(wm * 64 + mi * 16 + quad * 4 + r) * 68 + ni * 16 + l15] =
                            (_Float16)acc[mi][ni][r];
        }
        __syncthreads();
        const int cbase = n0 + hf * 64;
        if (n0 < 2048) {
            const int hh = (cbase & 1023) >> 6;
            _Float16* dst = (n0 < 1024 ? qh : kh) + (size_t)((b << 4) | hh) * 131072;
#pragma unroll
            for (int it = 0; it < 4; ++it) {
                int cc = it * 256 + t;
                int r = cc >> 3, c8 = cc & 7;
                half4 lo = *(const half4*)&SH[r * 68 + c8 * 8];
                half4 hi = *(const half4*)&SH[r * 68 + c8 * 8 + 4];
                half8 v;
#pragma unroll
                for (int j = 0; j < 4; ++j) { v[j] = lo[j]; v[j + 4] = hi[j]; }
                *(half8*)&dst[(size_t)(s0 + r) * 64 + c8 * 8] = v;
            }
        } else {
            const int hh = (cbase - 2048) >> 6;
            _Float16* dst = vth + (size_t)((b << 4) | hh) * 131072;
#pragma unroll
            for (int it = 0; it < 4; ++it) {
                int cc = it * 256 + t;
                int d = cc >> 4, s8 = cc & 15;
                half8 v;
#pragma unroll
                for (int j = 0; j < 8; ++j) v[j] = SH[(s8 * 8 + j) * 68 + d];
                *(half8*)&dst[(size_t)d * 2048 + s0 + s8 * 8] = v;
            }
        }
    }
}

// ---------------- GEMM2: out = aoh @ w_out^T + b_out -> fp32 ---------------------
// 64x128 tile (grid 8x64 = 512 blocks -> 2 blocks/CU), BK=32, 256 threads.
__global__ __launch_bounds__(256) void gemm_out(const _Float16* __restrict__ A,
                                                const float* __restrict__ W,
                                                float* __restrict__ C,
                                                const float* __restrict__ bias) {
    const int K = 1024, N = 1024;
    __shared__ _Float16 As[64 * 40];
    __shared__ _Float16 Bs[128 * 40];
    const int t = threadIdx.x;
    const int lane = t & 63, w = t >> 6;
    const int l15 = lane & 15, quad = lane >> 4;
    const int wm = w >> 1, wn = w & 1;
    const int m0 = blockIdx.y * 64, n0 = blockIdx.x * 128;

    floatx4 acc[2][4];
    const floatx4 zf = {0.f, 0.f, 0.f, 0.f};
#pragma unroll
    for (int i = 0; i < 2; ++i)
#pragma unroll
        for (int j = 0; j < 4; ++j) acc[i][j] = zf;

    for (int kt = 0; kt < K; kt += 32) {
        __syncthreads();
        {   // A: fp16 source
            int row = t >> 2, kc = t & 3;
            *(half8*)&As[row * 40 + kc * 8] =
                *(const half8*)&A[(size_t)(m0 + row) * K + kt + kc * 8];
        }
#pragma unroll
        for (int it = 0; it < 4; ++it) {        // B: fp32 source
            int cc = it * 256 + t;
            int row = cc >> 3, c4 = cc & 7;
            floatx4 wv = *(const floatx4*)&W[(size_t)(n0 + row) * K + kt + c4 * 4];
            half4 wh;
#pragma unroll
            for (int j = 0; j < 4; ++j) wh[j] = (_Float16)wv[j];
            *(half4*)&Bs[row * 40 + c4 * 4] = wh;
        }
        __syncthreads();
        half8 af[2], bfr[4];
#pragma unroll
        for (int i = 0; i < 2; ++i)
            af[i] = *(const half8*)&As[(wm * 32 + i * 16 + l15) * 40 + quad * 8];
#pragma unroll
        for (int i = 0; i < 4; ++i)
            bfr[i] = *(const half8*)&Bs[(wn * 64 + i * 16 + l15) * 40 + quad * 8];
#pragma unroll
        for (int mi = 0; mi < 2; ++mi)
#pragma unroll
            for (int ni = 0; ni < 4; ++ni)
                acc[mi][ni] = __builtin_amdgcn_mfma_f32_16x16x32_f16(af[mi], bfr[ni],
                                                                     acc[mi][ni], 0, 0, 0);
    }

#pragma unroll
    for (int mi = 0; mi < 2; ++mi) {
#pragma unroll
        for (int ni = 0; ni < 4; ++ni) {
            int col = n0 + wn * 64 + ni * 16 + l15;
            float bv = bias[col];
#pragma unroll
            for (int r = 0; r < 4; ++r) {
                int row = m0 + wm * 32 + mi * 16 + quad * 4 + r;
                C[(size_t)row * N + col] = acc[mi][ni][r] + bv;
            }
        }
    }
}

// pos(a) = 1 + a + a^2/2 + a^3/6  (Horner, 3 fma)
__device__ inline float s3pos(float a) {
    float h = fmaf(a, 0.16666667f, 0.5f);
    h = fmaf(a, h, 1.0f);
    return fmaf(a, h, 1.0f);
}

// ---------------- fused two-pass stablemax attention (S^T form, 4 waves) ---------
// grid (S/128, B*H), 256 threads. Wave w owns 32 q rows (w*32 + nh*16 + l15).
// Q fragments live in registers (loaded once from global); kf LDS reads are
// amortized over 2x the q rows vs round 5. P never touches LDS (permuted-key PV).
__global__ __launch_bounds__(256) void attn_kernel(const _Float16* __restrict__ qh,
                                                   const _Float16* __restrict__ kh,
                                                   const _Float16* __restrict__ vth,
                                                   _Float16* __restrict__ out) {
    __shared__ _Float16 SM[2 * 64 * 72];   // Ks | VTs (9 KB each); reused as O-stage
    _Float16* Ks = SM;
    _Float16* VTs = SM + 64 * 72;

    const int t = threadIdx.x;
    const int lane = t & 63, w = t >> 6;
    const int l15 = lane & 15, quad = lane >> 4;
    const int q0 = blockIdx.x * 128;
    const int bh = blockIdx.y;
    const int b = bh >> 4, h = bh & 15;

    const _Float16* Qp = qh + (size_t)bh * 131072 + q0 * 64;
    const _Float16* Kp = kh + (size_t)bh * 131072;
    const _Float16* VTp = vth + (size_t)bh * 131072;

    const floatx4 zf = {0.f, 0.f, 0.f, 0.f};

    // hoist Q fragments into registers: wave w rows w*32 + nh*16 + l15
    half8 qf[2][2];   // [nh][kk]
#pragma unroll
    for (int nh = 0; nh < 2; ++nh)
#pragma unroll
        for (int kk = 0; kk < 2; ++kk)
            qf[nh][kk] = *(const half8*)&Qp[(w * 32 + nh * 16 + l15) * 64 + kk * 32 + quad * 8];

    // ---------------- pass 1: row max over keys -----------------------------
    float rmax[2] = {-1.0e30f, -1.0e30f};

    for (int kt = 0; kt < 2048; kt += 64) {
        __syncthreads();
#pragma unroll
        for (int it = 0; it < 2; ++it) {   // K tile 64x64: 512 chunks / 256 thr
            int cc = it * 256 + t;
            int r = cc >> 3, c8 = cc & 7;
            *(half8*)&Ks[r * 72 + c8 * 8] = *(const half8*)&Kp[kt * 64 + cc * 8];
        }
        __syncthreads();
        floatx4 sa[4][2];
#pragma unroll
        for (int T = 0; T < 4; ++T) { sa[T][0] = zf; sa[T][1] = zf; }
#pragma unroll
        for (int kk = 0; kk < 2; ++kk) {
            half8 kf[4];
#pragma unroll
            for (int T = 0; T < 4; ++T)
                kf[T] = *(const half8*)&Ks[(T * 16 + l15) * 72 + kk * 32 + quad * 8];
#pragma unroll
            for (int T = 0; T < 4; ++T)
#pragma unroll
                for (int nh = 0; nh < 2; ++nh)
                    sa[T][nh] = __builtin_amdgcn_mfma_f32_16x16x32_f16(kf[T], qf[nh][kk],
                                                                      sa[T][nh], 0, 0, 0);
        }
#pragma unroll
        for (int T = 0; T < 4; ++T)
#pragma unroll
            for (int nh = 0; nh < 2; ++nh)
#pragma unroll
                for (int r = 0; r < 4; ++r)
                    rmax[nh] = fmaxf(rmax[nh], sa[T][nh][r]);
    }
#pragma unroll
    for (int nh = 0; nh < 2; ++nh) {
        rmax[nh] = fmaxf(rmax[nh], __shfl_xor(rmax[nh], 16, 64));
        rmax[nh] = fmaxf(rmax[nh], __shfl_xor(rmax[nh], 32, 64));
    }
    const float xm[2] = {-0.125f * rmax[0], -0.125f * rmax[1]};

    // ---------------- pass 2: p = s3(0.125*dot + xm); Sum p; P·V -------------
    float rsum[2] = {0.f, 0.f};
    floatx4 oacc[4][2];   // O^T: d-tile (4) x nh (2)
#pragma unroll
    for (int i = 0; i < 4; ++i) { oacc[i][0] = zf; oacc[i][1] = zf; }

    for (int kt = 0; kt < 2048; kt += 64) {
        __syncthreads();
#pragma unroll
        for (int it = 0; it < 2; ++it) {
            int cc = it * 256 + t;
            int r = cc >> 3, c8 = cc & 7;
            *(half8*)&Ks[r * 72 + c8 * 8] = *(const half8*)&Kp[kt * 64 + cc * 8];
            *(half8*)&VTs[r * 72 + c8 * 8] =
                *(const half8*)&VTp[(size_t)r * 2048 + kt + c8 * 8];
        }
        __syncthreads();
        floatx4 sa[4][2];
#pragma unroll
        for (int T = 0; T < 4; ++T) { sa[T][0] = zf; sa[T][1] = zf; }
#pragma unroll
        for (int kk = 0; kk < 2; ++kk) {
            half8 kf[4];
#pragma unroll
            for (int T = 0; T < 4; ++T)
                kf[T] = *(const half8*)&Ks[(T * 16 + l15) * 72 + kk * 32 + quad * 8];
#pragma unroll
            for (int T = 0; T < 4; ++T)
#pragma unroll
                for (int nh = 0; nh < 2; ++nh)
                    sa[T][nh] = __builtin_amdgcn_mfma_f32_16x16x32_f16(kf[T], qf[nh][kk],
                                                                      sa[T][nh], 0, 0, 0);
        }
        // s3 in-register; x <= 0 always (bit-identical recompute) -> s3 = rcp(pos(|x|))
        float p[2][4][4];
#pragma unroll
        for (int nh = 0; nh < 2; ++nh)
#pragma unroll
            for (int T = 0; T < 4; ++T)
#pragma unroll
                for (int r = 0; r < 4; ++r) {
                    float x = fmaf(sa[T][nh][r], 0.125f, xm[nh]);
                    float pv = __builtin_amdgcn_rcpf(s3pos(fabsf(x)));
                    p[nh][T][r] = pv;
                    rsum[nh] += pv;
                }
        // PV: O^T[d][q] += VT[d][key] * P[q][key], permuted key order
        // key(kappa = quad*8 + j) = c*32 + (j>>2)*16 + quad*4 + (j&3)
#pragma unroll
        for (int c = 0; c < 2; ++c) {
            half8 vf[4];
#pragma unroll
            for (int di = 0; di < 4; ++di) {
                half4 lo = *(const half4*)&VTs[(di * 16 + l15) * 72 + c * 32 + 4 * quad];
                half4 hi = *(const half4*)&VTs[(di * 16 + l15) * 72 + c * 32 + 16 + 4 * quad];
                half8 vv;
#pragma unroll
                for (int j = 0; j < 4; ++j) { vv[j] = lo[j]; vv[j + 4] = hi[j]; }
                vf[di] = vv;
            }
#pragma unroll
            for (int nh = 0; nh < 2; ++nh) {
                half8 pb;
#pragma unroll
                for (int j = 0; j < 8; ++j)
                    pb[j] = (_Float16)p[nh][2 * c + (j >> 2)][j & 3];
#pragma unroll
                for (int di = 0; di < 4; ++di)
                    oacc[di][nh] = __builtin_amdgcn_mfma_f32_16x16x32_f16(vf[di], pb,
                                                                         oacc[di][nh], 0, 0, 0);
            }
        }
    }

    // row sums across quads
#pragma unroll
    for (int nh = 0; nh < 2; ++nh) {
        rsum[nh] += __shfl_xor(rsum[nh], 16, 64);
        rsum[nh] += __shfl_xor(rsum[nh], 32, 64);
    }
    const float inv[2] = {1.0f / rsum[0], 1.0f / rsum[1]};

    // stage O (q-major) into LDS (reuse SM: 128 rows x stride 72 = 18 KB)
    __syncthreads();
    _Float16* Os = SM;
#pragma unroll
    for (int di = 0; di < 4; ++di) {
#pragma unroll
        for (int nh = 0; nh < 2; ++nh) {
            half4 hv;
#pragma unroll
            for (int r = 0; r < 4; ++r) hv[r] = (_Float16)(oacc[di][nh][r] * inv[nh]);
            *(half4*)&Os[(w * 32 + nh * 16 + l15) * 72 + di * 16 + quad * 4] = hv;
        }
    }
    __syncthreads();
    _Float16* Op = out + (size_t)(b * 2048 + q0) * 1024 + h * 64;
#pragma unroll
    for (int it = 0; it < 4; ++it) {
        int cc = it * 256 + t;
        int r = cc >> 3, c8 = cc & 7;
        *(half8*)&Op[(size_t)r * 1024 + c8 * 8] = *(const half8*)&Os[r * 72 + c8 * 8];
    }
}

// ---------------- launch ---------------------------------------------------------
extern "C" void kernel_launch(void* const* d_in, const int* in_sizes, int n_in,
                              void* d_out, int out_size, void* d_ws, size_t ws_size,
                              hipStream_t stream) {
    const float* x_f = (const float*)d_in[0];     // [2,2048,1024] fp32
    const float* wqkv_f = (const float*)d_in[1];  // [3072,1024] fp32
    const float* wout_f = (const float*)d_in[2];  // [1024,1024] fp32
    const float* bias_f = (const float*)d_in[3];  // [1024] fp32

    // workspace: 32 MB total
    char* ws = (char*)d_ws;
    _Float16* qh = (_Float16*)(ws);                   // [32][2048][64] fp16, 8 MB
    _Float16* kh = (_Float16*)(ws + 8388608);         // [32][2048][64] fp16, 8 MB
    _Float16* vth = (_Float16*)(ws + 16777216);       // [32][64][2048] fp16, 8 MB
    _Float16* aoh = (_Float16*)(ws + 25165824);       // [4096][1024]  fp16, 8 MB

    gemm_qkv<<<dim3(24, 32), 256, 0, stream>>>(x_f, wqkv_f, qh, kh, vth);
    attn_kernel<<<dim3(16, 32), 256, 0, stream>>>(qh, kh, vth, aoh);
    gemm_out<<<dim3(8, 64), 256, 0, stream>>>(aoh, wout_f, (float*)d_out, bias_f);
}

// Round 7
// 220.045 us; speedup vs baseline: 1.5923x; 1.0669x over previous
//
#include <hip/hip_runtime.h>

typedef _Float16 half8 __attribute__((ext_vector_type(8)));
typedef _Float16 half4 __attribute__((ext_vector_type(4)));
typedef float floatx4 __attribute__((ext_vector_type(4)));

__device__ __forceinline__ void gl_lds16(const _Float16* g, _Float16* l) {
    __builtin_amdgcn_global_load_lds(
        (const __attribute__((address_space(1))) void*)g,
        (__attribute__((address_space(3))) void*)l, 16, 0, 0);
}

// ---------------- fp32 -> fp16 one-time convert ---------------------------------
__global__ __launch_bounds__(256) void cvt_f32_f16(const floatx4* __restrict__ in,
                                                   half4* __restrict__ out, int n4) {
    int i = blockIdx.x * 256 + threadIdx.x;
    if (i >= n4) return;
    floatx4 v = in[i];
    half4 h;
#pragma unroll
    for (int j = 0; j < 4; ++j) h[j] = (_Float16)v[j];
    out[i] = h;
}

// ---------------- GEMM1: qkv = xh @ wqh^T -> head-major q/k/vt (fp16 in/out) -----
// M=4096, N=3072, K=1024. 128x128 tile, BK=32, 256 thr. m97-style DMA staging.
__global__ __launch_bounds__(256) void gemm_qkv(const _Float16* __restrict__ A,
                                                const _Float16* __restrict__ B,
                                                _Float16* __restrict__ qh,
                                                _Float16* __restrict__ kh,
                                                _Float16* __restrict__ vth) {
    const int K = 1024;
    __shared__ _Float16 SH[128 * 68];   // 17.4 KB; As 8KB | Bs 8KB; epilogue 128x68
    _Float16* As = SH;
    _Float16* Bs = SH + 4096;
    const int t = threadIdx.x;
    const int lane = t & 63, w = t >> 6;
    const int l15 = lane & 15, quad = lane >> 4;
    const int wm = w >> 1, wn = w & 1;
    const int m0 = blockIdx.y * 128, n0 = blockIdx.x * 128;

    floatx4 acc[4][4];
    const floatx4 zf = {0.f, 0.f, 0.f, 0.f};
#pragma unroll
    for (int i = 0; i < 4; ++i)
#pragma unroll
        for (int j = 0; j < 4; ++j) acc[i][j] = zf;

    for (int kt = 0; kt < K; kt += 32) {
        __syncthreads();
#pragma unroll
        for (int it = 0; it < 2; ++it) {    // 512 chunks of 16B per matrix
            int cc = it * 256 + t;
            int row = cc >> 2, kc = cc & 3;
            gl_lds16(&A[(size_t)(m0 + row) * K + kt + kc * 8], &As[cc * 8]);
            gl_lds16(&B[(size_t)(n0 + row) * K + kt + kc * 8], &Bs[cc * 8]);
        }
        __syncthreads();
        half8 af[4], bfr[4];
#pragma unroll
        for (int i = 0; i < 4; ++i)
            af[i] = *(const half8*)&As[(wm * 64 + i * 16 + l15) * 32 + quad * 8];
#pragma unroll
        for (int i = 0; i < 4; ++i)
            bfr[i] = *(const half8*)&Bs[(wn * 64 + i * 16 + l15) * 32 + quad * 8];
#pragma unroll
        for (int mi = 0; mi < 4; ++mi)
#pragma unroll
            for (int ni = 0; ni < 4; ++ni)
                acc[mi][ni] = __builtin_amdgcn_mfma_f32_16x16x32_f16(af[mi], bfr[ni],
                                                                     acc[mi][ni], 0, 0, 0);
    }

    // ---- epilogue: two 128x64 col-halves staged through LDS, coalesced writes ----
    const int b = m0 >> 11, s0 = m0 & 2047;
#pragma unroll
    for (int hf = 0; hf < 2; ++hf) {
        __syncthreads();
        if (wn == hf) {
#pragma unroll
            for (int mi = 0; mi < 4; ++mi)
#pragma unroll
                for (int ni = 0; ni < 4; ++ni)
#pragma unroll
                    for (int r = 0; r < 4; ++r)
                        SH[(wm * 64 + mi * 16 + quad * 4 + r) * 68 + ni * 16 + l15] =
                            (_Float16)acc[mi][ni][r];
        }
        __syncthreads();
        const int cbase = n0 + hf * 64;
        if (n0 < 2048) {
            const int hh = (cbase & 1023) >> 6;
            _Float16* dst = (n0 < 1024 ? qh : kh) + (size_t)((b << 4) | hh) * 131072;
#pragma unroll
            for (int it = 0; it < 4; ++it) {
                int cc = it * 256 + t;
                int r = cc >> 3, c8 = cc & 7;
                half4 lo = *(const half4*)&SH[r * 68 + c8 * 8];
                half4 hi = *(const half4*)&SH[r * 68 + c8 * 8 + 4];
                half8 v;
#pragma unroll
                for (int j = 0; j < 4; ++j) { v[j] = lo[j]; v[j + 4] = hi[j]; }
                *(half8*)&dst[(size_t)(s0 + r) * 64 + c8 * 8] = v;
            }
        } else {
            const int hh = (cbase - 2048) >> 6;
            _Float16* dst = vth + (size_t)((b << 4) | hh) * 131072;
#pragma unroll
            for (int it = 0; it < 4; ++it) {
                int cc = it * 256 + t;
                int d = cc >> 4, s8 = cc & 15;
                half8 v;
#pragma unroll
                for (int j = 0; j < 8; ++j) v[j] = SH[(s8 * 8 + j) * 68 + d];
                *(half8*)&dst[(size_t)d * 2048 + s0 + s8 * 8] = v;
            }
        }
    }
}

// ---------------- GEMM2: out = aoh @ woh^T + b_out -> fp32 -----------------------
// M=4096, N=1024, K=1024. 64x128 tile, BK=32, 256 thr, DMA staging.
__global__ __launch_bounds__(256) void gemm_out(const _Float16* __restrict__ A,
                                                const _Float16* __restrict__ B,
                                                float* __restrict__ C,
                                                const float* __restrict__ bias) {
    const int K = 1024, N = 1024;
    __shared__ _Float16 SH[6144];   // As 64x32 (4KB) | Bs 128x32 (8KB)
    _Float16* As = SH;
    _Float16* Bs = SH + 2048;
    const int t = threadIdx.x;
    const int lane = t & 63, w = t >> 6;
    const int l15 = lane & 15, quad = lane >> 4;
    const int wm = w >> 1, wn = w & 1;
    const int m0 = blockIdx.y * 64, n0 = blockIdx.x * 128;

    floatx4 acc[2][4];
    const floatx4 zf = {0.f, 0.f, 0.f, 0.f};
#pragma unroll
    for (int i = 0; i < 2; ++i)
#pragma unroll
        for (int j = 0; j < 4; ++j) acc[i][j] = zf;

    for (int kt = 0; kt < K; kt += 32) {
        __syncthreads();
        {   // A: 256 chunks of 16B
            int row = t >> 2, kc = t & 3;
            gl_lds16(&A[(size_t)(m0 + row) * K + kt + kc * 8], &As[t * 8]);
        }
#pragma unroll
        for (int it = 0; it < 2; ++it) {    // B: 512 chunks of 16B
            int cc = it * 256 + t;
            int row = cc >> 2, kc = cc & 3;
            gl_lds16(&B[(size_t)(n0 + row) * K + kt + kc * 8], &Bs[cc * 8]);
        }
        __syncthreads();
        half8 af[2], bfr[4];
#pragma unroll
        for (int i = 0; i < 2; ++i)
            af[i] = *(const half8*)&As[(wm * 32 + i * 16 + l15) * 32 + quad * 8];
#pragma unroll
        for (int i = 0; i < 4; ++i)
            bfr[i] = *(const half8*)&Bs[(wn * 64 + i * 16 + l15) * 32 + quad * 8];
#pragma unroll
        for (int mi = 0; mi < 2; ++mi)
#pragma unroll
            for (int ni = 0; ni < 4; ++ni)
                acc[mi][ni] = __builtin_amdgcn_mfma_f32_16x16x32_f16(af[mi], bfr[ni],
                                                                     acc[mi][ni], 0, 0, 0);
    }

#pragma unroll
    for (int mi = 0; mi < 2; ++mi) {
#pragma unroll
        for (int ni = 0; ni < 4; ++ni) {
            int col = n0 + wn * 64 + ni * 16 + l15;
            float bv = bias[col];
#pragma unroll
            for (int r = 0; r < 4; ++r) {
                int row = m0 + wm * 32 + mi * 16 + quad * 4 + r;
                C[(size_t)row * N + col] = acc[mi][ni][r] + bv;
            }
        }
    }
}

// pos(a) = 1 + a + a^2/2 + a^3/6  (Horner, 3 fma)
__device__ inline float s3pos(float a) {
    float h = fmaf(a, 0.16666667f, 0.5f);
    h = fmaf(a, h, 1.0f);
    return fmaf(a, h, 1.0f);
}

// ---------------- fused two-pass stablemax attention (S^T form, 4 waves) ---------
// grid (S/128, B*H), 256 threads. Wave w owns 32 q rows (w*32 + nh*16 + l15).
// Q fragments in registers; P never touches LDS (permuted-key PV).
__global__ __launch_bounds__(256) void attn_kernel(const _Float16* __restrict__ qh,
                                                   const _Float16* __restrict__ kh,
                                                   const _Float16* __restrict__ vth,
                                                   _Float16* __restrict__ out) {
    __shared__ _Float16 SM[2 * 64 * 72];   // Ks | VTs (9 KB each); reused as O-stage
    _Float16* Ks = SM;
    _Float16* VTs = SM + 64 * 72;

    const int t = threadIdx.x;
    const int lane = t & 63, w = t >> 6;
    const int l15 = lane & 15, quad = lane >> 4;
    const int q0 = blockIdx.x * 128;
    const int bh = blockIdx.y;
    const int b = bh >> 4, h = bh & 15;

    const _Float16* Qp = qh + (size_t)bh * 131072 + q0 * 64;
    const _Float16* Kp = kh + (size_t)bh * 131072;
    const _Float16* VTp = vth + (size_t)bh * 131072;

    const floatx4 zf = {0.f, 0.f, 0.f, 0.f};

    half8 qf[2][2];   // [nh][kk]
#pragma unroll
    for (int nh = 0; nh < 2; ++nh)
#pragma unroll
        for (int kk = 0; kk < 2; ++kk)
            qf[nh][kk] = *(const half8*)&Qp[(w * 32 + nh * 16 + l15) * 64 + kk * 32 + quad * 8];

    // ---------------- pass 1: row max over keys -----------------------------
    float rmax[2] = {-1.0e30f, -1.0e30f};

    for (int kt = 0; kt < 2048; kt += 64) {
        __syncthreads();
#pragma unroll
        for (int it = 0; it < 2; ++it) {
            int cc = it * 256 + t;
            int r = cc >> 3, c8 = cc & 7;
            *(half8*)&Ks[r * 72 + c8 * 8] = *(const half8*)&Kp[kt * 64 + cc * 8];
        }
        __syncthreads();
        floatx4 sa[4][2];
#pragma unroll
        for (int T = 0; T < 4; ++T) { sa[T][0] = zf; sa[T][1] = zf; }
#pragma unroll
        for (int kk = 0; kk < 2; ++kk) {
            half8 kf[4];
#pragma unroll
            for (int T = 0; T < 4; ++T)
                kf[T] = *(const half8*)&Ks[(T * 16 + l15) * 72 + kk * 32 + quad * 8];
#pragma unroll
            for (int T = 0; T < 4; ++T)
#pragma unroll
                for (int nh = 0; nh < 2; ++nh)
                    sa[T][nh] = __builtin_amdgcn_mfma_f32_16x16x32_f16(kf[T], qf[nh][kk],
                                                                      sa[T][nh], 0, 0, 0);
        }
#pragma unroll
        for (int T = 0; T < 4; ++T)
#pragma unroll
            for (int nh = 0; nh < 2; ++nh)
#pragma unroll
                for (int r = 0; r < 4; ++r)
                    rmax[nh] = fmaxf(rmax[nh], sa[T][nh][r]);
    }
#pragma unroll
    for (int nh = 0; nh < 2; ++nh) {
        rmax[nh] = fmaxf(rmax[nh], __shfl_xor(rmax[nh], 16, 64));
        rmax[nh] = fmaxf(rmax[nh], __shfl_xor(rmax[nh], 32, 64));
    }
    const float xm[2] = {-0.125f * rmax[0], -0.125f * rmax[1]};

    // ---------------- pass 2: p = s3(0.125*dot + xm); Sum p; P·V -------------
    float rsum[2] = {0.f, 0.f};
    floatx4 oacc[4][2];
#pragma unroll
    for (int i = 0; i < 4; ++i) { oacc[i][0] = zf; oacc[i][1] = zf; }

    for (int kt = 0; kt < 2048; kt += 64) {
        __syncthreads();
#pragma unroll
        for (int it = 0; it < 2; ++it) {
            int cc = it * 256 + t;
            int r = cc >> 3, c8 = cc & 7;
            *(half8*)&Ks[r * 72 + c8 * 8] = *(const half8*)&Kp[kt * 64 + cc * 8];
            *(half8*)&VTs[r * 72 + c8 * 8] =
                *(const half8*)&VTp[(size_t)r * 2048 + kt + c8 * 8];
        }
        __syncthreads();
        floatx4 sa[4][2];
#pragma unroll
        for (int T = 0; T < 4; ++T) { sa[T][0] = zf; sa[T][1] = zf; }
#pragma unroll
        for (int kk = 0; kk < 2; ++kk) {
            half8 kf[4];
#pragma unroll
            for (int T = 0; T < 4; ++T)
                kf[T] = *(const half8*)&Ks[(T * 16 + l15) * 72 + kk * 32 + quad * 8];
#pragma unroll
            for (int T = 0; T < 4; ++T)
#pragma unroll
                for (int nh = 0; nh < 2; ++nh)
                    sa[T][nh] = __builtin_amdgcn_mfma_f32_16x16x32_f16(kf[T], qf[nh][kk],
                                                                      sa[T][nh], 0, 0, 0);
        }
        float p[2][4][4];
#pragma unroll
        for (int nh = 0; nh < 2; ++nh)
#pragma unroll
            for (int T = 0; T < 4; ++T)
#pragma unroll
                for (int r = 0; r < 4; ++r) {
                    float x = fmaf(sa[T][nh][r], 0.125f, xm[nh]);
                    float pv = __builtin_amdgcn_rcpf(s3pos(fabsf(x)));
                    p[nh][T][r] = pv;
                    rsum[nh] += pv;
                }
        // PV with permuted key order: key(quad*8+j) = c*32 + (j>>2)*16 + quad*4 + (j&3)
#pragma unroll
        for (int c = 0; c < 2; ++c) {
            half8 vf[4];
#pragma unroll
            for (int di = 0; di < 4; ++di) {
                half4 lo = *(const half4*)&VTs[(di * 16 + l15) * 72 + c * 32 + 4 * quad];
                half4 hi = *(const half4*)&VTs[(di * 16 + l15) * 72 + c * 32 + 16 + 4 * quad];
                half8 vv;
#pragma unroll
                for (int j = 0; j < 4; ++j) { vv[j] = lo[j]; vv[j + 4] = hi[j]; }
                vf[di] = vv;
            }
#pragma unroll
            for (int nh = 0; nh < 2; ++nh) {
                half8 pb;
#pragma unroll
                for (int j = 0; j < 8; ++j)
                    pb[j] = (_Float16)p[nh][2 * c + (j >> 2)][j & 3];
#pragma unroll
                for (int di = 0; di < 4; ++di)
                    oacc[di][nh] = __builtin_amdgcn_mfma_f32_16x16x32_f16(vf[di], pb,
                                                                         oacc[di][nh], 0, 0, 0);
            }
        }
    }

#pragma unroll
    for (int nh = 0; nh < 2; ++nh) {
        rsum[nh] += __shfl_xor(rsum[nh], 16, 64);
        rsum[nh] += __shfl_xor(rsum[nh], 32, 64);
    }
    const float inv[2] = {1.0f / rsum[0], 1.0f / rsum[1]};

    __syncthreads();
    _Float16* Os = SM;
#pragma unroll
    for (int di = 0; di < 4; ++di) {
#pragma unroll
        for (int nh = 0; nh < 2; ++nh) {
            half4 hv;
#pragma unroll
            for (int r = 0; r < 4; ++r) hv[r] = (_Float16)(oacc[di][nh][r] * inv[nh]);
            *(half4*)&Os[(w * 32 + nh * 16 + l15) * 72 + di * 16 + quad * 4] = hv;
        }
    }
    __syncthreads();
    _Float16* Op = out + (size_t)(b * 2048 + q0) * 1024 + h * 64;
#pragma unroll
    for (int it = 0; it < 4; ++it) {
        int cc = it * 256 + t;
        int r = cc >> 3, c8 = cc & 7;
        *(half8*)&Op[(size_t)r * 1024 + c8 * 8] = *(const half8*)&Os[r * 72 + c8 * 8];
    }
}

// ---------------- launch ---------------------------------------------------------
extern "C" void kernel_launch(void* const* d_in, const int* in_sizes, int n_in,
                              void* d_out, int out_size, void* d_ws, size_t ws_size,
                              hipStream_t stream) {
    const float* x_f = (const float*)d_in[0];     // [2,2048,1024] fp32
    const float* wqkv_f = (const float*)d_in[1];  // [3072,1024] fp32
    const float* wout_f = (const float*)d_in[2];  // [1024,1024] fp32
    const float* bias_f = (const float*)d_in[3];  // [1024] fp32

    // workspace: 38 MB, with aliasing (aoh reuses xh; woh reuses wqh)
    char* ws = (char*)d_ws;
    _Float16* xh = (_Float16*)(ws);                   // [4096][1024] f16, 8 MB
    _Float16* aoh = xh;                               // alias: live after gemm_qkv
    _Float16* wqh = (_Float16*)(ws + 8388608);        // [3072][1024] f16, 6 MB
    _Float16* woh = wqh;                              // alias: live after gemm_qkv
    _Float16* qh = (_Float16*)(ws + 14680064);        // [32][2048][64] f16, 8 MB
    _Float16* kh = (_Float16*)(ws + 23068672);        // [32][2048][64] f16, 8 MB
    _Float16* vth = (_Float16*)(ws + 31457280);       // [32][64][2048] f16, 8 MB

    cvt_f32_f16<<<4096, 256, 0, stream>>>((const floatx4*)x_f, (half4*)xh, 1048576);
    cvt_f32_f16<<<3072, 256, 0, stream>>>((const floatx4*)wqkv_f, (half4*)wqh, 786432);
    gemm_qkv<<<dim3(24, 32), 256, 0, stream>>>(xh, wqh, qh, kh, vth);
    cvt_f32_f16<<<1024, 256, 0, stream>>>((const floatx4*)wout_f, (half4*)woh, 262144);
    attn_kernel<<<dim3(16, 32), 256, 0, stream>>>(qh, kh, vth, aoh);
    gemm_out<<<dim3(8, 64), 256, 0, stream>>>(aoh, woh, (float*)d_out, bias_f);
}

// Round 8
// 216.577 us; speedup vs baseline: 1.6178x; 1.0160x over previous
//
#include <hip/hip_runtime.h>

typedef _Float16 half8 __attribute__((ext_vector_type(8)));
typedef _Float16 half4 __attribute__((ext_vector_type(4)));
typedef float floatx4 __attribute__((ext_vector_type(4)));

__device__ __forceinline__ void gl_lds16(const _Float16* g, _Float16* l) {
    __builtin_amdgcn_global_load_lds(
        (const __attribute__((address_space(1))) void*)g,
        (__attribute__((address_space(3))) void*)l, 16, 0, 0);
}

// ---------------- fp32 -> fp16 one-time convert ---------------------------------
__global__ __launch_bounds__(256) void cvt_f32_f16(const floatx4* __restrict__ in,
                                                   half4* __restrict__ out, int n4) {
    int i = blockIdx.x * 256 + threadIdx.x;
    if (i >= n4) return;
    floatx4 v = in[i];
    half4 h;
#pragma unroll
    for (int j = 0; j < 4; ++j) h[j] = (_Float16)v[j];
    out[i] = h;
}

// ---------------- GEMM1: qkv = xh @ wqh^T -> head-major q/k/vt (fp16 in/out) -----
// M=4096, N=3072, K=1024. 128x128 tile, BK=32, 256 thr. m97-style DMA staging.
__global__ __launch_bounds__(256) void gemm_qkv(const _Float16* __restrict__ A,
                                                const _Float16* __restrict__ B,
                                                _Float16* __restrict__ qh,
                                                _Float16* __restrict__ kh,
                                                _Float16* __restrict__ vth) {
    const int K = 1024;
    __shared__ _Float16 SH[128 * 68];   // 17.4 KB; As 8KB | Bs 8KB; epilogue 128x68
    _Float16* As = SH;
    _Float16* Bs = SH + 4096;
    const int t = threadIdx.x;
    const int lane = t & 63, w = t >> 6;
    const int l15 = lane & 15, quad = lane >> 4;
    const int wm = w >> 1, wn = w & 1;
    const int m0 = blockIdx.y * 128, n0 = blockIdx.x * 128;

    floatx4 acc[4][4];
    const floatx4 zf = {0.f, 0.f, 0.f, 0.f};
#pragma unroll
    for (int i = 0; i < 4; ++i)
#pragma unroll
        for (int j = 0; j < 4; ++j) acc[i][j] = zf;

    for (int kt = 0; kt < K; kt += 32) {
        __syncthreads();
#pragma unroll
        for (int it = 0; it < 2; ++it) {    // 512 chunks of 16B per matrix
            int cc = it * 256 + t;
            int row = cc >> 2, kc = cc & 3;
            gl_lds16(&A[(size_t)(m0 + row) * K + kt + kc * 8], &As[cc * 8]);
            gl_lds16(&B[(size_t)(n0 + row) * K + kt + kc * 8], &Bs[cc * 8]);
        }
        __syncthreads();
        half8 af[4], bfr[4];
#pragma unroll
        for (int i = 0; i < 4; ++i)
            af[i] = *(const half8*)&As[(wm * 64 + i * 16 + l15) * 32 + quad * 8];
#pragma unroll
        for (int i = 0; i < 4; ++i)
            bfr[i] = *(const half8*)&Bs[(wn * 64 + i * 16 + l15) * 32 + quad * 8];
#pragma unroll
        for (int mi = 0; mi < 4; ++mi)
#pragma unroll
            for (int ni = 0; ni < 4; ++ni)
                acc[mi][ni] = __builtin_amdgcn_mfma_f32_16x16x32_f16(af[mi], bfr[ni],
                                                                     acc[mi][ni], 0, 0, 0);
    }

    // ---- epilogue: two 128x64 col-halves staged through LDS, coalesced writes ----
    const int b = m0 >> 11, s0 = m0 & 2047;
#pragma unroll
    for (int hf = 0; hf < 2; ++hf) {
        __syncthreads();
        if (wn == hf) {
#pragma unroll
            for (int mi = 0; mi < 4; ++mi)
#pragma unroll
                for (int ni = 0; ni < 4; ++ni)
#pragma unroll
                    for (int r = 0; r < 4; ++r)
                        SH[(wm * 64 + mi * 16 + quad * 4 + r) * 68 + ni * 16 + l15] =
                            (_Float16)acc[mi][ni][r];
        }
        __syncthreads();
        const int cbase = n0 + hf * 64;
        if (n0 < 2048) {
            const int hh = (cbase & 1023) >> 6;
            _Float16* dst = (n0 < 1024 ? qh : kh) + (size_t)((b << 4) | hh) * 131072;
#pragma unroll
            for (int it = 0; it < 4; ++it) {
                int cc = it * 256 + t;
                int r = cc >> 3, c8 = cc & 7;
                half4 lo = *(const half4*)&SH[r * 68 + c8 * 8];
                half4 hi = *(const half4*)&SH[r * 68 + c8 * 8 + 4];
                half8 v;
#pragma unroll
                for (int j = 0; j < 4; ++j) { v[j] = lo[j]; v[j + 4] = hi[j]; }
                *(half8*)&dst[(size_t)(s0 + r) * 64 + c8 * 8] = v;
            }
        } else {
            const int hh = (cbase - 2048) >> 6;
            _Float16* dst = vth + (size_t)((b << 4) | hh) * 131072;
#pragma unroll
            for (int it = 0; it < 4; ++it) {
                int cc = it * 256 + t;
                int d = cc >> 4, s8 = cc & 15;
                half8 v;
#pragma unroll
                for (int j = 0; j < 8; ++j) v[j] = SH[(s8 * 8 + j) * 68 + d];
                *(half8*)&dst[(size_t)d * 2048 + s0 + s8 * 8] = v;
            }
        }
    }
}

// ---------------- GEMM2: out = aoh @ woh^T + b_out -> fp32 -----------------------
// M=4096, N=1024, K=1024. 64x128 tile, BK=32, 256 thr, DMA staging.
__global__ __launch_bounds__(256) void gemm_out(const _Float16* __restrict__ A,
                                                const _Float16* __restrict__ B,
                                                float* __restrict__ C,
                                                const float* __restrict__ bias) {
    const int K = 1024, N = 1024;
    __shared__ _Float16 SH[6144];   // As 64x32 (4KB) | Bs 128x32 (8KB)
    _Float16* As = SH;
    _Float16* Bs = SH + 2048;
    const int t = threadIdx.x;
    const int lane = t & 63, w = t >> 6;
    const int l15 = lane & 15, quad = lane >> 4;
    const int wm = w >> 1, wn = w & 1;
    const int m0 = blockIdx.y * 64, n0 = blockIdx.x * 128;

    floatx4 acc[2][4];
    const floatx4 zf = {0.f, 0.f, 0.f, 0.f};
#pragma unroll
    for (int i = 0; i < 2; ++i)
#pragma unroll
        for (int j = 0; j < 4; ++j) acc[i][j] = zf;

    for (int kt = 0; kt < K; kt += 32) {
        __syncthreads();
        {   // A: 256 chunks of 16B
            int row = t >> 2, kc = t & 3;
            gl_lds16(&A[(size_t)(m0 + row) * K + kt + kc * 8], &As[t * 8]);
        }
#pragma unroll
        for (int it = 0; it < 2; ++it) {    // B: 512 chunks of 16B
            int cc = it * 256 + t;
            int row = cc >> 2, kc = cc & 3;
            gl_lds16(&B[(size_t)(n0 + row) * K + kt + kc * 8], &Bs[cc * 8]);
        }
        __syncthreads();
        half8 af[2], bfr[4];
#pragma unroll
        for (int i = 0; i < 2; ++i)
            af[i] = *(const half8*)&As[(wm * 32 + i * 16 + l15) * 32 + quad * 8];
#pragma unroll
        for (int i = 0; i < 4; ++i)
            bfr[i] = *(const half8*)&Bs[(wn * 64 + i * 16 + l15) * 32 + quad * 8];
#pragma unroll
        for (int mi = 0; mi < 2; ++mi)
#pragma unroll
            for (int ni = 0; ni < 4; ++ni)
                acc[mi][ni] = __builtin_amdgcn_mfma_f32_16x16x32_f16(af[mi], bfr[ni],
                                                                     acc[mi][ni], 0, 0, 0);
    }

#pragma unroll
    for (int mi = 0; mi < 2; ++mi) {
#pragma unroll
        for (int ni = 0; ni < 4; ++ni) {
            int col = n0 + wn * 64 + ni * 16 + l15;
            float bv = bias[col];
#pragma unroll
            for (int r = 0; r < 4; ++r) {
                int row = m0 + wm * 32 + mi * 16 + quad * 4 + r;
                C[(size_t)row * N + col] = acc[mi][ni][r] + bv;
            }
        }
    }
}

// pos(a) = 1 + a + a^2/2 + a^3/6  (Horner, 3 fma)
__device__ inline float s3pos(float a) {
    float h = fmaf(a, 0.16666667f, 0.5f);
    h = fmaf(a, h, 1.0f);
    return fmaf(a, h, 1.0f);
}

// ---------------- fused two-pass stablemax attention (S^T form, 4 waves) ---------
// grid (S/128, B*H), 256 threads. Wave w owns 32 q rows (w*32 + nh*16 + l15).
// Q fragments in registers; P never touches LDS (permuted-key PV).
__global__ __launch_bounds__(256) void attn_kernel(const _Float16* __restrict__ qh,
                                                   const _Float16* __restrict__ kh,
                                                   const _Float16* __restrict__ vth,
                                                   _Float16* __restrict__ out) {
    __shared__ _Float16 SM[2 * 64 * 72];   // Ks | VTs (9 KB each); reused as O-stage
    _Float16* Ks = SM;
    _Float16* VTs = SM + 64 * 72;

    const int t = threadIdx.x;
    const int lane = t & 63, w = t >> 6;
    const int l15 = lane & 15, quad = lane >> 4;
    const int q0 = blockIdx.x * 128;
    const int bh = blockIdx.y;
    const int b = bh >> 4, h = bh & 15;

    const _Float16* Qp = qh + (size_t)bh * 131072 + q0 * 64;
    const _Float16* Kp = kh + (size_t)bh * 131072;
    const _Float16* VTp = vth + (size_t)bh * 131072;

    const floatx4 zf = {0.f, 0.f, 0.f, 0.f};

    half8 qf[2][2];   // [nh][kk]
#pragma unroll
    for (int nh = 0; nh < 2; ++nh)
#pragma unroll
        for (int kk = 0; kk < 2; ++kk)
            qf[nh][kk] = *(const half8*)&Qp[(w * 32 + nh * 16 + l15) * 64 + kk * 32 + quad * 8];

    // ---------------- pass 1: row max over keys -----------------------------
    float rmax[2] = {-1.0e30f, -1.0e30f};

    for (int kt = 0; kt < 2048; kt += 64) {
        __syncthreads();
#pragma unroll
        for (int it = 0; it < 2; ++it) {
            int cc = it * 256 + t;
            int r = cc >> 3, c8 = cc & 7;
            *(half8*)&Ks[r * 72 + c8 * 8] = *(const half8*)&Kp[kt * 64 + cc * 8];
        }
        __syncthreads();
        floatx4 sa[4][2];
#pragma unroll
        for (int T = 0; T < 4; ++T) { sa[T][0] = zf; sa[T][1] = zf; }
#pragma unroll
        for (int kk = 0; kk < 2; ++kk) {
            half8 kf[4];
#pragma unroll
            for (int T = 0; T < 4; ++T)
                kf[T] = *(const half8*)&Ks[(T * 16 + l15) * 72 + kk * 32 + quad * 8];
#pragma unroll
            for (int T = 0; T < 4; ++T)
#pragma unroll
                for (int nh = 0; nh < 2; ++nh)
                    sa[T][nh] = __builtin_amdgcn_mfma_f32_16x16x32_f16(kf[T], qf[nh][kk],
                                                                      sa[T][nh], 0, 0, 0);
        }
#pragma unroll
        for (int T = 0; T < 4; ++T)
#pragma unroll
            for (int nh = 0; nh < 2; ++nh)
#pragma unroll
                for (int r = 0; r < 4; ++r)
                    rmax[nh] = fmaxf(rmax[nh], sa[T][nh][r]);
    }
#pragma unroll
    for (int nh = 0; nh < 2; ++nh) {
        rmax[nh] = fmaxf(rmax[nh], __shfl_xor(rmax[nh], 16, 64));
        rmax[nh] = fmaxf(rmax[nh], __shfl_xor(rmax[nh], 32, 64));
    }
    const float xm[2] = {-0.125f * rmax[0], -0.125f * rmax[1]};

    // ---------------- pass 2: p = s3(0.125*dot + xm); Sum p; P·V -------------
    float rsum[2] = {0.f, 0.f};
    floatx4 oacc[4][2];
#pragma unroll
    for (int i = 0; i < 4; ++i) { oacc[i][0] = zf; oacc[i][1] = zf; }

    for (int kt = 0; kt < 2048; kt += 64) {
        __syncthreads();
#pragma unroll
        for (int it = 0; it < 2; ++it) {
            int cc = it * 256 + t;
            int r = cc >> 3, c8 = cc & 7;
            *(half8*)&Ks[r * 72 + c8 * 8] = *(const half8*)&Kp[kt * 64 + cc * 8];
            *(half8*)&VTs[r * 72 + c8 * 8] =
                *(const half8*)&VTp[(size_t)r * 2048 + kt + c8 * 8];
        }
        __syncthreads();
        floatx4 sa[4][2];
#pragma unroll
        for (int T = 0; T < 4; ++T) { sa[T][0] = zf; sa[T][1] = zf; }
#pragma unroll
        for (int kk = 0; kk < 2; ++kk) {
            half8 kf[4];
#pragma unroll
            for (int T = 0; T < 4; ++T)
                kf[T] = *(const half8*)&Ks[(T * 16 + l15) * 72 + kk * 32 + quad * 8];
#pragma unroll
            for (int T = 0; T < 4; ++T)
#pragma unroll
                for (int nh = 0; nh < 2; ++nh)
                    sa[T][nh] = __builtin_amdgcn_mfma_f32_16x16x32_f16(kf[T], qf[nh][kk],
                                                                      sa[T][nh], 0, 0, 0);
        }
        float p[2][4][4];
#pragma unroll
        for (int nh = 0; nh < 2; ++nh)
#pragma unroll
            for (int T = 0; T < 4; ++T)
#pragma unroll
                for (int r = 0; r < 4; ++r) {
                    float x = fmaf(sa[T][nh][r], 0.125f, xm[nh]);
                    float pv = __builtin_amdgcn_rcpf(s3pos(fabsf(x)));
                    p[nh][T][r] = pv;
                    rsum[nh] += pv;
                }
        // PV with permuted key order: key(quad*8+j) = c*32 + (j>>2)*16 + quad*4 + (j&3)
#pragma unroll
        for (int c = 0; c < 2; ++c) {
            half8 vf[4];
#pragma unroll
            for (int di = 0; di < 4; ++di) {
                half4 lo = *(const half4*)&VTs[(di * 16 + l15) * 72 + c * 32 + 4 * quad];
                half4 hi = *(const half4*)&VTs[(di * 16 + l15) * 72 + c * 32 + 16 + 4 * quad];
                half8 vv;
#pragma unroll
                for (int j = 0; j < 4; ++j) { vv[j] = lo[j]; vv[j + 4] = hi[j]; }
                vf[di] = vv;
            }
#pragma unroll
            for (int nh = 0; nh < 2; ++nh) {
                half8 pb;
#pragma unroll
                for (int j = 0; j < 8; ++j)
                    pb[j] = (_Float16)p[nh][2 * c + (j >> 2)][j & 3];
#pragma unroll
                for (int di = 0; di < 4; ++di)
                    oacc[di][nh] = __builtin_amdgcn_mfma_f32_16x16x32_f16(vf[di], pb,
                                                                         oacc[di][nh], 0, 0, 0);
            }
        }
    }

#pragma unroll
    for (int nh = 0; nh < 2; ++nh) {
        rsum[nh] += __shfl_xor(rsum[nh], 16, 64);
        rsum[nh] += __shfl_xor(rsum[nh], 32, 64);
    }
    const float inv[2] = {1.0f / rsum[0], 1.0f / rsum[1]};

    __syncthreads();
    _Float16* Os = SM;
#pragma unroll
    for (int di = 0; di < 4; ++di) {
#pragma unroll
        for (int nh = 0; nh < 2; ++nh) {
            half4 hv;
#pragma unroll
            for (int r = 0; r < 4; ++r) hv[r] = (_Float16)(oacc[di][nh][r] * inv[nh]);
            *(half4*)&Os[(w * 32 + nh * 16 + l15) * 72 + di * 16 + quad * 4] = hv;
        }
    }
    __syncthreads();
    _Float16* Op = out + (size_t)(b * 2048 + q0) * 1024 + h * 64;
#pragma unroll
    for (int it = 0; it < 4; ++it) {
        int cc = it * 256 + t;
        int r = cc >> 3, c8 = cc & 7;
        *(half8*)&Op[(size_t)r * 1024 + c8 * 8] = *(const half8*)&Os[r * 72 + c8 * 8];
    }
}

// ---------------- launch ---------------------------------------------------------
extern "C" void kernel_launch(void* const* d_in, const int* in_sizes, int n_in,
                              void* d_out, int out_size, void* d_ws, size_t ws_size,
                              hipStream_t stream) {
    const float* x_f = (const float*)d_in[0];     // [2,2048,1024] fp32
    const float* wqkv_f = (const float*)d_in[1];  // [3072,1024] fp32
    const float* wout_f = (const float*)d_in[2];  // [1024,1024] fp32
    const float* bias_f = (const float*)d_in[3];  // [1024] fp32

    // workspace: 38 MB, with aliasing (aoh reuses xh; woh reuses wqh)
    char* ws = (char*)d_ws;
    _Float16* xh = (_Float16*)(ws);                   // [4096][1024] f16, 8 MB
    _Float16* aoh = xh;                               // alias: live after gemm_qkv
    _Float16* wqh = (_Float16*)(ws + 8388608);        // [3072][1024] f16, 6 MB
    _Float16* woh = wqh;                              // alias: live after gemm_qkv
    _Float16* qh = (_Float16*)(ws + 14680064);        // [32][2048][64] f16, 8 MB
    _Float16* kh = (_Float16*)(ws + 23068672);        // [32][2048][64] f16, 8 MB
    _Float16* vth = (_Float16*)(ws + 31457280);       // [32][64][2048] f16, 8 MB

    cvt_f32_f16<<<4096, 256, 0, stream>>>((const floatx4*)x_f, (half4*)xh, 1048576);
    cvt_f32_f16<<<3072, 256, 0, stream>>>((const floatx4*)wqkv_f, (half4*)wqh, 786432);
    gemm_qkv<<<dim3(24, 32), 256, 0, stream>>>(xh, wqh, qh, kh, vth);
    cvt_f32_f16<<<1024, 256, 0, stream>>>((const floatx4*)wout_f, (half4*)woh, 262144);
    attn_kernel<<<dim3(16, 32), 256, 0, stream>>>(qh, kh, vth, aoh);
    gemm_out<<<dim3(8, 64), 256, 0, stream>>>(aoh, woh, (float*)d_out, bias_f);
}